// Round 13
// baseline (1437.673 us; speedup 1.0000x reference)
//
#include <hip/hip_runtime.h>
#include <math.h>

#define NE 160000
#define NN 10000

#define DEV __device__ __forceinline__

typedef float v2f __attribute__((ext_vector_type(2)));

DEV float fsilu(float x) { return x / (1.0f + __expf(-x)); }
DEV float fsig(float x)  { return 1.0f / (1.0f + __expf(-x)); }

// ---- bf16 pack/unpack helpers (RNE) ----
DEV unsigned pack2(float a, float b) {
  unsigned ua = __float_as_uint(a); ua += 0x7FFFu + ((ua >> 16) & 1u);
  unsigned ub = __float_as_uint(b); ub += 0x7FFFu + ((ub >> 16) & 1u);
  return (ua >> 16) | (ub & 0xFFFF0000u);
}
DEV float unlo(unsigned u) { return __uint_as_float(u << 16); }
DEV float unhi(unsigned u) { return __uint_as_float(u & 0xFFFF0000u); }

// ---- fp8 e4m3 (OCP, HW-converted) ----
DEV unsigned packf8_4(float a, float b, float c, float d) {
  int r = __builtin_amdgcn_cvt_pk_fp8_f32(a, b, 0, false);
  r = __builtin_amdgcn_cvt_pk_fp8_f32(c, d, r, true);
  return (unsigned)r;
}
template<bool HI>
DEV v2f up2(unsigned u) { return __builtin_amdgcn_cvt_pk_f32_fp8((int)u, HI); }

// dot of 16 fp8 values (one uint4) against q[0..16)
DEV float dot16(uint4 u, const float* q, float d) {
  v2f f;
  f = up2<false>(u.x); d = fmaf(f.x, q[0],  d); d = fmaf(f.y, q[1],  d);
  f = up2<true >(u.x); d = fmaf(f.x, q[2],  d); d = fmaf(f.y, q[3],  d);
  f = up2<false>(u.y); d = fmaf(f.x, q[4],  d); d = fmaf(f.y, q[5],  d);
  f = up2<true >(u.y); d = fmaf(f.x, q[6],  d); d = fmaf(f.y, q[7],  d);
  f = up2<false>(u.z); d = fmaf(f.x, q[8],  d); d = fmaf(f.y, q[9],  d);
  f = up2<true >(u.z); d = fmaf(f.x, q[10], d); d = fmaf(f.y, q[11], d);
  f = up2<false>(u.w); d = fmaf(f.x, q[12], d); d = fmaf(f.y, q[13], d);
  f = up2<true >(u.w); d = fmaf(f.x, q[14], d); d = fmaf(f.y, q[15], d);
  return d;
}
// o[0..16) += pk * fp8x16(u)
DEV void acc16(uint4 u, float pk, float* o) {
  v2f f;
  f = up2<false>(u.x); o[0]  = fmaf(pk, f.x, o[0]);  o[1]  = fmaf(pk, f.y, o[1]);
  f = up2<true >(u.x); o[2]  = fmaf(pk, f.x, o[2]);  o[3]  = fmaf(pk, f.y, o[3]);
  f = up2<false>(u.y); o[4]  = fmaf(pk, f.x, o[4]);  o[5]  = fmaf(pk, f.y, o[5]);
  f = up2<true >(u.y); o[6]  = fmaf(pk, f.x, o[6]);  o[7]  = fmaf(pk, f.y, o[7]);
  f = up2<false>(u.z); o[8]  = fmaf(pk, f.x, o[8]);  o[9]  = fmaf(pk, f.y, o[9]);
  f = up2<true >(u.z); o[10] = fmaf(pk, f.x, o[10]); o[11] = fmaf(pk, f.y, o[11]);
  f = up2<false>(u.w); o[12] = fmaf(pk, f.x, o[12]); o[13] = fmaf(pk, f.y, o[13]);
  f = up2<true >(u.w); o[14] = fmaf(pk, f.x, o[14]); o[15] = fmaf(pk, f.y, o[15]);
}

// 2-edge, 32-out GEMM chunk (w block-uniform -> s_load broadcast)
template<int K>
DEV void g2(const float* __restrict__ x0, const float* __restrict__ x1,
            const float* __restrict__ w, float (&a0)[32], float (&a1)[32]) {
#pragma unroll 4
  for (int k = 0; k < K; k += 4) {
    const float4 u = *(const float4*)(x0 + k);
    const float4 v = *(const float4*)(x1 + k);
    const float* wr = w + (size_t)k * 64;
#pragma unroll
    for (int j = 0; j < 32; ++j) { float ww = wr[j];       a0[j] = fmaf(u.x, ww, a0[j]); a1[j] = fmaf(v.x, ww, a1[j]); }
#pragma unroll
    for (int j = 0; j < 32; ++j) { float ww = wr[64 + j];  a0[j] = fmaf(u.y, ww, a0[j]); a1[j] = fmaf(v.y, ww, a1[j]); }
#pragma unroll
    for (int j = 0; j < 32; ++j) { float ww = wr[128 + j]; a0[j] = fmaf(u.z, ww, a0[j]); a1[j] = fmaf(v.z, ww, a1[j]); }
#pragma unroll
    for (int j = 0; j < 32; ++j) { float ww = wr[192 + j]; a0[j] = fmaf(u.w, ww, a0[j]); a1[j] = fmaf(v.w, ww, a1[j]); }
  }
}

// 1-edge, 32-out GEMM chunk
template<int K>
DEV void g1(const float* __restrict__ x, const float* __restrict__ w,
            float (&a)[32]) {
#pragma unroll 4
  for (int k = 0; k < K; k += 4) {
    const float4 u = *(const float4*)(x + k);
    const float* wr = w + (size_t)k * 64;
#pragma unroll
    for (int j = 0; j < 32; ++j) a[j] = fmaf(u.x, wr[j], a[j]);
#pragma unroll
    for (int j = 0; j < 32; ++j) a[j] = fmaf(u.y, wr[64 + j], a[j]);
#pragma unroll
    for (int j = 0; j < 32; ++j) a[j] = fmaf(u.z, wr[128 + j], a[j]);
#pragma unroll
    for (int j = 0; j < 32; ++j) a[j] = fmaf(u.w, wr[192 + j], a[j]);
  }
}

// GEMV chunk from packed-bf16 row (32 uints = 64 values)
DEV void gp32(const unsigned (&zp)[32], const float* __restrict__ w, float (&a)[32]) {
#pragma unroll 8
  for (int t = 0; t < 32; ++t) {
    const float x0 = unlo(zp[t]), x1 = unhi(zp[t]);
    const float* wr = w + (size_t)(2 * t) * 64;
#pragma unroll
    for (int j = 0; j < 32; ++j) a[j] = fmaf(x0, wr[j], a[j]);
#pragma unroll
    for (int j = 0; j < 32; ++j) a[j] = fmaf(x1, wr[64 + j], a[j]);
  }
}
// 64-out version (two 32-chunks)
DEV void gp64(const unsigned (&zp)[32], const float* __restrict__ w,
              float (&a)[32], float (&b)[32]) {
#pragma unroll 8
  for (int t = 0; t < 32; ++t) {
    const float x0 = unlo(zp[t]), x1 = unhi(zp[t]);
    const float* wr = w + (size_t)(2 * t) * 64;
#pragma unroll
    for (int j = 0; j < 32; ++j) a[j] = fmaf(x0, wr[j], a[j]);
#pragma unroll
    for (int j = 0; j < 32; ++j) b[j] = fmaf(x0, wr[32 + j], b[j]);
#pragma unroll
    for (int j = 0; j < 32; ++j) a[j] = fmaf(x1, wr[64 + j], a[j]);
#pragma unroll
    for (int j = 0; j < 32; ++j) b[j] = fmaf(x1, wr[96 + j], b[j]);
  }
}

DEV void ldrow(const unsigned* __restrict__ p, unsigned (&r)[32]) {
#pragma unroll
  for (int t = 0; t < 8; ++t) {
    uint4 u = ((const uint4*)p)[t];
    r[4*t] = u.x; r[4*t+1] = u.y; r[4*t+2] = u.z; r[4*t+3] = u.w;
  }
}
DEV void storef8(unsigned* dst, const float (&a)[32]) {   // 8 uints (fp8)
#pragma unroll
  for (int t = 0; t < 2; ++t)
    ((uint4*)dst)[t] = make_uint4(
        packf8_4(a[16*t+0],  a[16*t+1],  a[16*t+2],  a[16*t+3]),
        packf8_4(a[16*t+4],  a[16*t+5],  a[16*t+6],  a[16*t+7]),
        packf8_4(a[16*t+8],  a[16*t+9],  a[16*t+10], a[16*t+11]),
        packf8_4(a[16*t+12], a[16*t+13], a[16*t+14], a[16*t+15]));
}
DEV void storebf64(unsigned* dst, const float (&a)[64]) {  // 32 uints
#pragma unroll
  for (int t = 0; t < 8; ++t)
    ((uint4*)dst)[t] = make_uint4(pack2(a[8*t], a[8*t+1]), pack2(a[8*t+2], a[8*t+3]),
                                  pack2(a[8*t+4], a[8*t+5]), pack2(a[8*t+6], a[8*t+7]));
}
DEV void store32(float* dst, const float (&a)[32]) {
#pragma unroll
  for (int j = 0; j < 32; j += 4)
    *(float4*)(dst + j) = make_float4(a[j], a[j+1], a[j+2], a[j+3]);
}

// ---------- CSR build over edges[0] (rows) ----------
__global__ void __launch_bounds__(256)
k_count(const int* __restrict__ edges, int* __restrict__ icnt) {
  int e = blockIdx.x * 256 + threadIdx.x;
  if (e < NE) atomicAdd(&icnt[edges[e]], 1);
}

__global__ void __launch_bounds__(256)
k_scan(const int* __restrict__ icnt, int* __restrict__ ioffs) {
  __shared__ int part[256];
  const int t = threadIdx.x;
  const int base = t * 40;
  int loc[40];
  int s = 0;
#pragma unroll
  for (int i = 0; i < 40; ++i) {
    int idx = base + i;
    int v = (idx < NN) ? icnt[idx] : 0;
    loc[i] = v; s += v;
  }
  part[t] = s;
  __syncthreads();
  for (int off = 1; off < 256; off <<= 1) {
    int v = (t >= off) ? part[t - off] : 0;
    __syncthreads();
    part[t] += v;
    __syncthreads();
  }
  int run = (t == 0) ? 0 : part[t - 1];
#pragma unroll
  for (int i = 0; i < 40; ++i) {
    int idx = base + i;
    if (idx < NN) { ioffs[idx] = run; run += loc[i]; }
  }
  if (t == 255) ioffs[NN] = NE;
}

__global__ void __launch_bounds__(256)
k_fill(const int* __restrict__ edges, const int* __restrict__ ioffs,
       int* __restrict__ icur, int* __restrict__ eidx) {
  int e = blockIdx.x * 256 + threadIdx.x;
  if (e >= NE) return;
  int r = edges[e];
  int p = atomicAdd(&icur[r], 1);
  eidx[ioffs[r] + p] = e;
}

// ---------- chem layer 1: 272 -> 64 silu (2 edges/thread, y-split) ----------
__global__ void __launch_bounds__(128)
k_chem1(const float* __restrict__ h, const float* __restrict__ na,
        const float* __restrict__ ea, const int* __restrict__ edges,
        const float* __restrict__ w1, const float* __restrict__ b1,
        float* __restrict__ act1c) {
  const int tid = threadIdx.x;
  const int e0 = blockIdx.x * 256 + tid, e1 = e0 + 128;
  const int co = blockIdx.y * 32;
  const int r0 = edges[e0], c0 = edges[NE + e0];
  const int r1 = edges[e1], c1 = edges[NE + e1];
  float a0[32], a1[32];
#pragma unroll
  for (int j = 0; j < 32; ++j) { a0[j] = b1[co + j]; a1[j] = a0[j]; }
  g2<64>(h  + (size_t)r0 * 64, h  + (size_t)r1 * 64, w1 + co,            a0, a1);
  g2<64>(h  + (size_t)c0 * 64, h  + (size_t)c1 * 64, w1 +  64 * 64 + co, a0, a1);
  g2<64>(na + (size_t)r0 * 64, na + (size_t)r1 * 64, w1 + 128 * 64 + co, a0, a1);
  g2<64>(na + (size_t)c0 * 64, na + (size_t)c1 * 64, w1 + 192 * 64 + co, a0, a1);
  g2<16>(ea + (size_t)e0 * 16, ea + (size_t)e1 * 16, w1 + 256 * 64 + co, a0, a1);
#pragma unroll
  for (int j = 0; j < 32; ++j) { a0[j] = fsilu(a0[j]); a1[j] = fsilu(a1[j]); }
  store32(act1c + (size_t)e0 * 64 + co, a0);
  store32(act1c + (size_t)e1 * 64 + co, a1);
}

// ---------- pos layer 1: 36 -> 64 silu ----------
__global__ void __launch_bounds__(256)
k_pos1(const float* __restrict__ coord, const float* __restrict__ nv,
       const float* __restrict__ ea, const int* __restrict__ edges,
       const float* __restrict__ w1, const float* __restrict__ b1,
       float* __restrict__ act1p) {
  const int e = blockIdx.x * 256 + threadIdx.x;
  const int co = blockIdx.y * 32;
  const int r = edges[e], c = edges[NE + e];

  float dx = coord[r * 3 + 0] - coord[c * 3 + 0];
  float dy = coord[r * 3 + 1] - coord[c * 3 + 1];
  float dz = coord[r * 3 + 2] - coord[c * 3 + 2];
  float nrm = sqrtf(dx * dx + dy * dy + dz * dz);
  float inv = 1.0f / (nrm + 1e-8f);
  dx *= inv; dy *= inv; dz *= inv;
  float ir = dx * dx + dy * dy + dz * dz;

  float in[36];
#pragma unroll
  for (int v = 0; v < 5; ++v) {
    float s = 0.f;
#pragma unroll
    for (int d = 0; d < 3; ++d)
      s += nv[(size_t)r * 15 + v * 3 + d] * nv[(size_t)c * 15 + v * 3 + d];
    in[v] = s;
  }
  {
    float cexp = -0.5f;
#pragma unroll
    for (int k = 0; k < 15; ++k) { in[5 + k] = __expf(ir * cexp); cexp *= (1.0f / 2.25f); }
  }
#pragma unroll
  for (int k = 0; k < 16; k += 4) {
    float4 e4 = *(const float4*)(ea + (size_t)e * 16 + k);
    in[20 + k] = e4.x; in[21 + k] = e4.y; in[22 + k] = e4.z; in[23 + k] = e4.w;
  }

  float acc[32];
#pragma unroll
  for (int j = 0; j < 32; ++j) acc[j] = b1[co + j];
#pragma unroll
  for (int k = 0; k < 36; ++k) {
    const float x = in[k];
    const float* wr = w1 + (size_t)k * 64 + co;
#pragma unroll
    for (int j = 0; j < 32; ++j) acc[j] = fmaf(x, wr[j], acc[j]);
  }
#pragma unroll
  for (int j = 0; j < 32; ++j) acc[j] = fsilu(acc[j]);
  store32(act1p + (size_t)e * 64 + co, acc);
}

// ---------- layer 2 of both MLPs (2 edges/thread, y-split) ----------
__global__ void __launch_bounds__(128)
k_l2(const float* __restrict__ act1c, const float* __restrict__ act1p,
     const float* __restrict__ w2c, const float* __restrict__ b2c,
     const float* __restrict__ w2p, const float* __restrict__ b2p,
     float* __restrict__ chem, float* __restrict__ pos) {
  const int tid = threadIdx.x;
  const int e0 = blockIdx.x * 256 + tid, e1 = e0 + 128;
  const int co = blockIdx.y * 32;
  float a0[32], a1[32];
#pragma unroll
  for (int j = 0; j < 32; ++j) { a0[j] = b2c[co + j]; a1[j] = a0[j]; }
  g2<64>(act1c + (size_t)e0 * 64, act1c + (size_t)e1 * 64, w2c + co, a0, a1);
#pragma unroll
  for (int j = 0; j < 32; ++j) { a0[j] = fsilu(a0[j]); a1[j] = fsilu(a1[j]); }
  store32(chem + (size_t)e0 * 64 + co, a0);
  store32(chem + (size_t)e1 * 64 + co, a1);
#pragma unroll
  for (int j = 0; j < 32; ++j) { a0[j] = b2p[co + j]; a1[j] = a0[j]; }
  g2<64>(act1p + (size_t)e0 * 64, act1p + (size_t)e1 * 64, w2p + co, a0, a1);
#pragma unroll
  for (int j = 0; j < 32; ++j) { a0[j] = fsilu(a0[j]); a1[j] = fsilu(a1[j]); }
  store32(pos + (size_t)e0 * 64 + co, a0);
  store32(pos + (size_t)e1 * 64 + co, a1);
}

// ---------- z0 = silu(chem@Wsh+b)*pos; partial att-gate dot into ae ----------
__global__ void __launch_bounds__(128)
k_z(const float* __restrict__ chem, const float* __restrict__ pos,
    const float* __restrict__ wsh, const float* __restrict__ bsh,
    const float* __restrict__ watt,
    float* __restrict__ z, float* __restrict__ ae) {
  const int tid = threadIdx.x;
  const int e0 = blockIdx.x * 256 + tid, e1 = e0 + 128;
  const int co = blockIdx.y * 32;
  float a0[32], a1[32];
#pragma unroll
  for (int j = 0; j < 32; ++j) { a0[j] = bsh[co + j]; a1[j] = a0[j]; }
  g2<64>(chem + (size_t)e0 * 64, chem + (size_t)e1 * 64, wsh + co, a0, a1);
  float ap0 = 0.f, ap1 = 0.f;
#pragma unroll
  for (int j = 0; j < 32; j += 4) {
    float4 p0 = *(const float4*)(pos + (size_t)e0 * 64 + co + j);
    float4 p1 = *(const float4*)(pos + (size_t)e1 * 64 + co + j);
    a0[j+0] = fsilu(a0[j+0]) * p0.x; a0[j+1] = fsilu(a0[j+1]) * p0.y;
    a0[j+2] = fsilu(a0[j+2]) * p0.z; a0[j+3] = fsilu(a0[j+3]) * p0.w;
    a1[j+0] = fsilu(a1[j+0]) * p1.x; a1[j+1] = fsilu(a1[j+1]) * p1.y;
    a1[j+2] = fsilu(a1[j+2]) * p1.z; a1[j+3] = fsilu(a1[j+3]) * p1.w;
  }
#pragma unroll
  for (int j = 0; j < 32; ++j) {
    float ww = watt[co + j];
    ap0 = fmaf(a0[j], ww, ap0); ap1 = fmaf(a1[j], ww, ap1);
  }
  store32(z + (size_t)e0 * 64 + co, a0);
  store32(z + (size_t)e1 * 64 + co, a1);
  atomicAdd(&ae[e0], ap0);
  atomicAdd(&ae[e1], ap1);
}

// ---------- scalars: gated z -> bf16, u/x heads, x_trans atomics, be[4] ----------
__global__ void __launch_bounds__(256)
k_scalars(const float* __restrict__ coord, const int* __restrict__ edges,
          const float* __restrict__ chem, const float* __restrict__ pos,
          const float* __restrict__ ae, const float* __restrict__ batt,
          const float* __restrict__ wu1, const float* __restrict__ bu1,
          const float* __restrict__ wu2, const float* __restrict__ bu2,
          const float* __restrict__ wx1, const float* __restrict__ bx1,
          const float* __restrict__ wx2, const float* __restrict__ bx2,
          const float* __restrict__ wb, const float* __restrict__ z,
          unsigned* __restrict__ zb, float* __restrict__ be,
          float* __restrict__ x_sum, float* __restrict__ cntf) {
  const int e = blockIdx.x * 256 + threadIdx.x;
  const int r = edges[e], c = edges[NE + e];
  const float* zr = z + (size_t)e * 64;
  const float sg = fsig(batt[0] + ae[e]);

  float zv[64];
#pragma unroll
  for (int j = 0; j < 64; j += 4) {
    float4 z4 = *(const float4*)(zr + j);
    zv[j+0] = z4.x * sg; zv[j+1] = z4.y * sg; zv[j+2] = z4.z * sg; zv[j+3] = z4.w * sg;
  }
  unsigned* zrow = zb + (size_t)e * 32;
#pragma unroll
  for (int t = 0; t < 8; ++t)
    ((uint4*)zrow)[t] = make_uint4(pack2(zv[8*t], zv[8*t+1]), pack2(zv[8*t+2], zv[8*t+3]),
                                   pack2(zv[8*t+4], zv[8*t+5]), pack2(zv[8*t+6], zv[8*t+7]));
#pragma unroll
  for (int hd = 0; hd < 4; ++hd) {
    float b = 0.f;
#pragma unroll
    for (int k = 0; k < 64; ++k) b = fmaf(zv[k], wb[hd * 64 + k], b);
    be[(size_t)hd * NE + e] = b;
  }

  const float* crow = chem + (size_t)e * 64;
  float u = bu2[0];
#pragma unroll 1
  for (int cc = 0; cc < 64; cc += 32) {
    float acc[32];
#pragma unroll
    for (int j = 0; j < 32; ++j) acc[j] = bu1[cc + j];
    g1<64>(crow, wu1 + cc, acc);
#pragma unroll
    for (int j = 0; j < 32; ++j) u = fmaf(fsilu(acc[j]), wu2[cc + j], u);
  }
  const float* prow = pos + (size_t)e * 64;
  float xs = bx2[0];
#pragma unroll 1
  for (int cc = 0; cc < 64; cc += 32) {
    float acc[32];
#pragma unroll
    for (int j = 0; j < 32; ++j) acc[j] = bx1[cc + j];
    g1<64>(prow, wx1 + cc, acc);
#pragma unroll
    for (int j = 0; j < 32; ++j) xs = fmaf(fsilu(acc[j]), wx2[cc + j], xs);
  }

  float dx = coord[r * 3 + 0] - coord[c * 3 + 0];
  float dy = coord[r * 3 + 1] - coord[c * 3 + 1];
  float dz = coord[r * 3 + 2] - coord[c * 3 + 2];
  float nrm = sqrtf(dx * dx + dy * dy + dz * dz);
  float inv = 1.0f / (nrm + 1e-8f);
  float t = u * xs;
  atomicAdd(&x_sum[r * 3 + 0], dx * inv * t);
  atomicAdd(&x_sum[r * 3 + 1], dy * inv * t);
  atomicAdd(&x_sum[r * 3 + 2], dz * inv * t);
  atomicAdd(&cntf[r], 1.0f);
}

// ---------- all-head k/v projection -> interleaved fp8 records (128B: k||v) ----------
__global__ void __launch_bounds__(256)
k_proj(const unsigned* __restrict__ zb, const float* __restrict__ wk,
       const float* __restrict__ wv, unsigned* __restrict__ kvh) {
  const int e = blockIdx.x * 256 + threadIdx.x;
  const int hd = blockIdx.y;          // 0..3
  const float* wk_h = wk + hd * 4096;
  const float* wv_h = wv + hd * 4096;
  unsigned zp[32];
  ldrow(zb + (size_t)e * 32, zp);
  unsigned* rec = kvh + ((size_t)hd * NE + e) * 32;   // [k:16u | v:16u]
  float acc[32];
#pragma unroll
  for (int j = 0; j < 32; ++j) acc[j] = 0.f;
  gp32(zp, wk_h, acc);       storef8(rec, acc);
#pragma unroll
  for (int j = 0; j < 32; ++j) acc[j] = 0.f;
  gp32(zp, wk_h + 32, acc);  storef8(rec + 8, acc);
#pragma unroll
  for (int j = 0; j < 32; ++j) acc[j] = 0.f;
  gp32(zp, wv_h, acc);       storef8(rec + 16, acc);
#pragma unroll
  for (int j = 0; j < 32; ++j) acc[j] = 0.f;
  gp32(zp, wv_h + 32, acc);  storef8(rec + 24, acc);
}

// ---------- attention (all 4 heads), interleaved fp8 k||v records ----------
__global__ void __launch_bounds__(256)
k_attn(const unsigned* __restrict__ zb, const unsigned* __restrict__ kvh,
       const float* __restrict__ be, const int* __restrict__ klist,
       const float* __restrict__ wq, const float* __restrict__ wg,
       const float* __restrict__ bg, unsigned* __restrict__ hob) {
  const int e = blockIdx.x * 256 + threadIdx.x;
  const int hd = blockIdx.y;          // 0..3
  const float* wq_h = wq + hd * 4096;
  const float* wg_h = wg + hd * 4096;
  const uint4* kv4 = (const uint4*)(kvh + (size_t)hd * NE * 32);  // 8 uint4/record
  const float* bb_h = be + (size_t)hd * NE;

  unsigned zp[32];
  ldrow(zb + (size_t)e * 32, zp);

  float qa[32], qb[32];
#pragma unroll
  for (int j = 0; j < 32; ++j) { qa[j] = 0.f; qb[j] = 0.f; }
  gp64(zp, wq_h, qa, qb);
#pragma unroll
  for (int j = 0; j < 32; ++j) { qa[j] *= 0.125f; qb[j] *= 0.125f; }

  int i2[8], j2[8];
#pragma unroll
  for (int kn = 0; kn < 8; ++kn) {
    i2[kn] = klist[(size_t)e * 16 + kn];
    j2[kn] = klist[(size_t)e * 16 + 8 + kn];
  }
  // alpha pass: k-half of each record (first 4 uint4 of the 128B line)
  float alpha[8];
#pragma unroll 2
  for (int kn = 0; kn < 8; ++kn) {
    if (i2[kn] < 0) { alpha[kn] = -10000.0f; continue; }
    const uint4* kr = kv4 + (size_t)i2[kn] * 8;
    uint4 u0 = kr[0], u1 = kr[1], u2 = kr[2], u3 = kr[3];
    float d = 0.f;
    d = dot16(u0, qa,      d);
    d = dot16(u1, qa + 16, d);
    d = dot16(u2, qb,      d);
    d = dot16(u3, qb + 16, d);
    alpha[kn] = d + bb_h[j2[kn]];
  }
  float mx = alpha[0];
#pragma unroll
  for (int kn = 1; kn < 8; ++kn) mx = fmaxf(mx, alpha[kn]);
  float p[8], s = 0.f;
#pragma unroll
  for (int kn = 0; kn < 8; ++kn) { p[kn] = __expf(alpha[kn] - mx); s += p[kn]; }
  float is = 1.0f / s;
#pragma unroll
  for (int kn = 0; kn < 8; ++kn) p[kn] *= is;

  // ov pass: v-half (second 4 uint4 of the same line -> L2-hot)
  float ov[64];
#pragma unroll
  for (int j = 0; j < 64; ++j) ov[j] = 0.f;
#pragma unroll 2
  for (int kn = 0; kn < 8; ++kn) {
    int vi = (i2[kn] < 0) ? (NE - 1) : i2[kn];   // jax v[-1] wraps
    const uint4* vr = kv4 + (size_t)vi * 8 + 4;
    uint4 u0 = vr[0], u1 = vr[1], u2 = vr[2], u3 = vr[3];
    const float pk = p[kn];
    acc16(u0, pk, ov +  0);
    acc16(u1, pk, ov + 16);
    acc16(u2, pk, ov + 32);
    acc16(u3, pk, ov + 48);
  }
  // gate
  {
    float ga[32], gb2[32];
#pragma unroll
    for (int j = 0; j < 32; ++j) { ga[j] = bg[hd * 64 + j]; gb2[j] = bg[hd * 64 + 32 + j]; }
    gp64(zp, wg_h, ga, gb2);
#pragma unroll
    for (int j = 0; j < 32; ++j) { ov[j] *= fsig(ga[j]); ov[32 + j] *= fsig(gb2[j]); }
  }
  storebf64(hob + ((size_t)hd * NE + e) * 32, ov);
}

// ---------- output projection (all heads), per-edge m row (non-atomic) ----------
__global__ void __launch_bounds__(256)
k_mout(const unsigned* __restrict__ hob, const float* __restrict__ wout,
       float* __restrict__ medge) {
  const int e = blockIdx.x * 256 + threadIdx.x;
  float mm[64];
#pragma unroll
  for (int j = 0; j < 64; ++j) mm[j] = 0.f;
#pragma unroll 1
  for (int hd = 0; hd < 4; ++hd) {
    const unsigned* row = hob + ((size_t)hd * NE + e) * 32;
    unsigned hp[32];
    ldrow(row, hp);
    const float* wo = wout + (size_t)hd * 4096;
#pragma unroll 4
    for (int t = 0; t < 32; ++t) {
      const float x0 = unlo(hp[t]), x1 = unhi(hp[t]);
      const float* wr = wo + (size_t)(2 * t) * 64;
#pragma unroll
      for (int j = 0; j < 64; ++j) mm[j] = fmaf(x0, wr[j], mm[j]);
#pragma unroll
      for (int j = 0; j < 64; ++j) mm[j] = fmaf(x1, wr[64 + j], mm[j]);
    }
  }
  float* mr = medge + (size_t)e * 64;
#pragma unroll
  for (int j = 0; j < 64; j += 4)
    *(float4*)(mr + j) = make_float4(mm[j], mm[j+1], mm[j+2], mm[j+3]);
}

// ---------- CSR gather: per-node segment sum of medge ----------
__global__ void __launch_bounds__(256)
k_nodesum(const float* __restrict__ medge, const int* __restrict__ ioffs,
          const int* __restrict__ eidx, float* __restrict__ m_sum) {
  const int wid = threadIdx.x >> 6, lane = threadIdx.x & 63;
  const int n = blockIdx.x * 4 + wid;
  if (n >= NN) return;
  const int beg = ioffs[n], end = ioffs[n + 1];
  float acc = 0.f;
  for (int i = beg; i < end; ++i) {
    int e = eidx[i];
    acc += medge[(size_t)e * 64 + lane];
  }
  m_sum[(size_t)n * 64 + lane] = acc;
}

// ---------- final node update ----------
__global__ void __launch_bounds__(256)
k_final(const float* __restrict__ h, const float* __restrict__ na,
        const float* __restrict__ coord, const float* __restrict__ icoord,
        const float* __restrict__ m_sum, const float* __restrict__ x_sum,
        const float* __restrict__ cntf, const float* __restrict__ bout,
        const float* __restrict__ wh1, const float* __restrict__ bh1,
        const float* __restrict__ wh2, const float* __restrict__ bh2,
        float* __restrict__ scr, float* __restrict__ out) {
  int n = blockIdx.x * 256 + threadIdx.x;
  if (n >= NN) return;
  float cn = cntf[n];
  float invc = 1.0f / fmaxf(cn, 1.0f);
  float bsc = (cn > 0.f) ? 1.0f : 0.0f;   // empty segment => m_agg = 0 (no bout)

#pragma unroll
  for (int d = 0; d < 3; ++d)
    out[(size_t)NN * 64 + n * 3 + d] =
        0.2f * icoord[n * 3 + d] + 0.8f * coord[n * 3 + d] + x_sum[n * 3 + d] * invc;

  const float* hr = h  + (size_t)n * 64;
  const float* nr = na + (size_t)n * 64;
  const float* mr = m_sum + (size_t)n * 64;
  float* srow = scr + (size_t)n * 64;

#pragma unroll 1
  for (int cc = 0; cc < 64; cc += 32) {
    float acc[32];
#pragma unroll
    for (int j = 0; j < 32; ++j) acc[j] = bh1[cc + j];
    g1<64>(hr, wh1 + cc, acc);
    g1<64>(nr, wh1 + 64 * 64 + cc, acc);
#pragma unroll 4
    for (int k = 0; k < 64; k += 4) {
      float4 m4 = *(const float4*)(mr + k);
      float xv[4] = { fmaf(m4.x, invc, bout[k] * bsc), fmaf(m4.y, invc, bout[k+1] * bsc),
                      fmaf(m4.z, invc, bout[k+2] * bsc), fmaf(m4.w, invc, bout[k+3] * bsc) };
#pragma unroll
      for (int q = 0; q < 4; ++q) {
        const float* wr = wh1 + (size_t)(128 + k + q) * 64 + cc;
        const float x = xv[q];
#pragma unroll
        for (int j = 0; j < 32; ++j) acc[j] = fmaf(x, wr[j], acc[j]);
      }
    }
#pragma unroll
    for (int j = 0; j < 32; ++j) acc[j] = fsilu(acc[j]);
    store32(srow + cc, acc);
  }
#pragma unroll 1
  for (int cc = 0; cc < 64; cc += 32) {
    float acc[32];
#pragma unroll
    for (int j = 0; j < 32; ++j) acc[j] = bh2[cc + j];
    g1<64>(srow, wh2 + cc, acc);
#pragma unroll
    for (int j = 0; j < 32; j += 4) {
      float4 h4 = *(const float4*)(hr + cc + j);
      *(float4*)(out + (size_t)n * 64 + cc + j) =
          make_float4(acc[j] + h4.x, acc[j+1] + h4.y, acc[j+2] + h4.z, acc[j+3] + h4.w);
    }
  }
}

extern "C" void kernel_launch(void* const* d_in, const int* in_sizes, int n_in,
                              void* d_out, int out_size, void* d_ws, size_t ws_size,
                              hipStream_t stream) {
  (void)in_sizes; (void)n_in; (void)out_size; (void)ws_size;
  const float* h      = (const float*)d_in[0];
  const float* coord  = (const float*)d_in[1];
  const int*   edges  = (const int*)  d_in[2];
  const float* nvecs  = (const float*)d_in[3];
  const float* ea     = (const float*)d_in[4];
  const float* na     = (const float*)d_in[5];
  const float* icoord = (const float*)d_in[6];
  const int*   klist  = (const int*)  d_in[7];
  const float* w_chem1 = (const float*)d_in[8];
  const float* b_chem1 = (const float*)d_in[9];
  const float* w_chem2 = (const float*)d_in[10];
  const float* b_chem2 = (const float*)d_in[11];
  const float* w_pos1  = (const float*)d_in[12];
  const float* b_pos1  = (const float*)d_in[13];
  const float* w_pos2  = (const float*)d_in[14];
  const float* b_pos2  = (const float*)d_in[15];
  const float* w_sh    = (const float*)d_in[16];
  const float* b_sh    = (const float*)d_in[17];
  const float* w_att   = (const float*)d_in[18];
  const float* b_att   = (const float*)d_in[19];
  const float* wq      = (const float*)d_in[20];
  const float* wk      = (const float*)d_in[21];
  const float* wv      = (const float*)d_in[22];
  const float* wb      = (const float*)d_in[23];
  const float* wg      = (const float*)d_in[24];
  const float* bg      = (const float*)d_in[25];
  const float* w_out   = (const float*)d_in[26];
  const float* b_out   = (const float*)d_in[27];
  const float* wu1     = (const float*)d_in[28];
  const float* bu1     = (const float*)d_in[29];
  const float* wu2     = (const float*)d_in[30];
  const float* bu2     = (const float*)d_in[31];
  const float* wx1     = (const float*)d_in[32];
  const float* bx1     = (const float*)d_in[33];
  const float* wx2     = (const float*)d_in[34];
  const float* bx2     = (const float*)d_in[35];
  const float* wh1     = (const float*)d_in[36];
  const float* bh1     = (const float*)d_in[37];
  const float* wh2     = (const float*)d_in[38];
  const float* bh2     = (const float*)d_in[39];

  float* out = (float*)d_out;
  float* ws  = (float*)d_ws;
  // Phase-reused regions (NE*64 floats each):
  //  R1+R2: act1c/act1p -> kvh (4 heads, interleaved fp8, 82MB) -> medge in R1
  //  R3+R4: chem/pos    -> hob (4 heads, bf16)
  float* R1 = ws;
  float* R2 = R1 + (size_t)NE * 64;
  float* R3 = R2 + (size_t)NE * 64;
  float* R4 = R3 + (size_t)NE * 64;
  float* zbf   = R4 + (size_t)NE * 64;      // NE*32 floats (bf16 gated z)
  float* ae    = zbf + (size_t)NE * 32;     // NE (zeroed)
  float* x_sum = ae + NE;                   // NN*3 (zeroed)
  float* cntf  = x_sum + (size_t)NN * 3;    // NN (zeroed)
  int*   icnt  = (int*)(cntf + NN);         // NN (zeroed)
  int*   icur  = icnt + NN;                 // NN (zeroed)
  float* m_sum = (float*)(icur + NN);       // NN*64
  float* be    = m_sum + (size_t)NN * 64;   // 4*NE
  float* nscr  = be + (size_t)4 * NE;       // NN*64
  int*   ioffs = (int*)(nscr + (size_t)NN * 64);  // NN+1
  int*   eidx  = ioffs + (NN + 1);          // NE

  unsigned* kvh = (unsigned*)R1;   // [4][NE][32] interleaved fp8 (spans R1+R2)
  unsigned* hob = (unsigned*)R3;   // [4][NE][32] bf16 (spans R3+R4)
  unsigned* zb  = (unsigned*)zbf;
  float* medge = R1;               // after attention (kvh dead)

  (void)hipMemsetAsync(ae, 0, ((size_t)NE + NN * 3 + NN + NN + NN) * sizeof(float), stream);

  dim3 b128(128), b256(256);
  dim3 gs2(NE / 256, 2);
  dim3 gs4(NE / 256, 4);
  dim3 gflat(NE / 256);

  // CSR build (independent of the MLP pipeline)
  k_count<<<gflat, b256, 0, stream>>>(edges, icnt);
  k_scan <<<dim3(1), b256, 0, stream>>>(icnt, ioffs);
  k_fill <<<gflat, b256, 0, stream>>>(edges, ioffs, icur, eidx);

  k_chem1<<<gs2, b128, 0, stream>>>(h, na, ea, edges, w_chem1, b_chem1, R1);
  k_pos1 <<<gs2, b256, 0, stream>>>(coord, nvecs, ea, edges, w_pos1, b_pos1, R2);
  k_l2   <<<gs2, b128, 0, stream>>>(R1, R2, w_chem2, b_chem2, w_pos2, b_pos2, R3, R4);
  k_z    <<<gs2, b128, 0, stream>>>(R3, R4, w_sh, b_sh, w_att, R1, ae);
  k_scalars<<<gflat, b256, 0, stream>>>(coord, edges, R3, R4, ae, b_att,
                                        wu1, bu1, wu2, bu2, wx1, bx1, wx2, bx2, wb,
                                        R1, zb, be, x_sum, cntf);
  // all 4 heads in one pass each
  k_proj <<<gs4, b256, 0, stream>>>(zb, wk, wv, kvh);
  k_attn <<<gs4, b256, 0, stream>>>(zb, kvh, be, klist, wq, wg, bg, hob);
  k_mout <<<gflat, b256, 0, stream>>>(hob, w_out, medge);
  k_nodesum<<<dim3((NN + 3) / 4), b256, 0, stream>>>(medge, ioffs, eidx, m_sum);
  k_final<<<dim3((NN + 255) / 256), b256, 0, stream>>>(h, na, coord, icoord, m_sum, x_sum,
                                                       cntf, b_out, wh1, bh1, wh2, bh2,
                                                       nscr, out);
}

// Round 14
// 1420.840 us; speedup vs baseline: 1.0118x; 1.0118x over previous
//
#include <hip/hip_runtime.h>
#include <math.h>

#define NE 160000
#define NN 10000

#define DEV __device__ __forceinline__

typedef float v2f __attribute__((ext_vector_type(2)));

DEV float fsilu(float x) { return x / (1.0f + __expf(-x)); }
DEV float fsig(float x)  { return 1.0f / (1.0f + __expf(-x)); }

// ---- bf16 pack/unpack helpers (RNE) ----
DEV unsigned pack2(float a, float b) {
  unsigned ua = __float_as_uint(a); ua += 0x7FFFu + ((ua >> 16) & 1u);
  unsigned ub = __float_as_uint(b); ub += 0x7FFFu + ((ub >> 16) & 1u);
  return (ua >> 16) | (ub & 0xFFFF0000u);
}
DEV float unlo(unsigned u) { return __uint_as_float(u << 16); }
DEV float unhi(unsigned u) { return __uint_as_float(u & 0xFFFF0000u); }

// ---- fp8 e4m3 (OCP, HW-converted) ----
DEV unsigned packf8_4(float a, float b, float c, float d) {
  int r = __builtin_amdgcn_cvt_pk_fp8_f32(a, b, 0, false);
  r = __builtin_amdgcn_cvt_pk_fp8_f32(c, d, r, true);
  return (unsigned)r;
}
template<bool HI>
DEV v2f up2(unsigned u) { return __builtin_amdgcn_cvt_pk_f32_fp8((int)u, HI); }

// dot of 16 fp8 values (one uint4) against q[0..16)
DEV float dot16(uint4 u, const float* q, float d) {
  v2f f;
  f = up2<false>(u.x); d = fmaf(f.x, q[0],  d); d = fmaf(f.y, q[1],  d);
  f = up2<true >(u.x); d = fmaf(f.x, q[2],  d); d = fmaf(f.y, q[3],  d);
  f = up2<false>(u.y); d = fmaf(f.x, q[4],  d); d = fmaf(f.y, q[5],  d);
  f = up2<true >(u.y); d = fmaf(f.x, q[6],  d); d = fmaf(f.y, q[7],  d);
  f = up2<false>(u.z); d = fmaf(f.x, q[8],  d); d = fmaf(f.y, q[9],  d);
  f = up2<true >(u.z); d = fmaf(f.x, q[10], d); d = fmaf(f.y, q[11], d);
  f = up2<false>(u.w); d = fmaf(f.x, q[12], d); d = fmaf(f.y, q[13], d);
  f = up2<true >(u.w); d = fmaf(f.x, q[14], d); d = fmaf(f.y, q[15], d);
  return d;
}
// o[0..16) += pk * fp8x16(u)
DEV void acc16(uint4 u, float pk, float* o) {
  v2f f;
  f = up2<false>(u.x); o[0]  = fmaf(pk, f.x, o[0]);  o[1]  = fmaf(pk, f.y, o[1]);
  f = up2<true >(u.x); o[2]  = fmaf(pk, f.x, o[2]);  o[3]  = fmaf(pk, f.y, o[3]);
  f = up2<false>(u.y); o[4]  = fmaf(pk, f.x, o[4]);  o[5]  = fmaf(pk, f.y, o[5]);
  f = up2<true >(u.y); o[6]  = fmaf(pk, f.x, o[6]);  o[7]  = fmaf(pk, f.y, o[7]);
  f = up2<false>(u.z); o[8]  = fmaf(pk, f.x, o[8]);  o[9]  = fmaf(pk, f.y, o[9]);
  f = up2<true >(u.z); o[10] = fmaf(pk, f.x, o[10]); o[11] = fmaf(pk, f.y, o[11]);
  f = up2<false>(u.w); o[12] = fmaf(pk, f.x, o[12]); o[13] = fmaf(pk, f.y, o[13]);
  f = up2<true >(u.w); o[14] = fmaf(pk, f.x, o[14]); o[15] = fmaf(pk, f.y, o[15]);
}

// 2-edge, 32-out GEMM chunk (w block-uniform -> s_load broadcast)
template<int K>
DEV void g2(const float* __restrict__ x0, const float* __restrict__ x1,
            const float* __restrict__ w, float (&a0)[32], float (&a1)[32]) {
#pragma unroll 4
  for (int k = 0; k < K; k += 4) {
    const float4 u = *(const float4*)(x0 + k);
    const float4 v = *(const float4*)(x1 + k);
    const float* wr = w + (size_t)k * 64;
#pragma unroll
    for (int j = 0; j < 32; ++j) { float ww = wr[j];       a0[j] = fmaf(u.x, ww, a0[j]); a1[j] = fmaf(v.x, ww, a1[j]); }
#pragma unroll
    for (int j = 0; j < 32; ++j) { float ww = wr[64 + j];  a0[j] = fmaf(u.y, ww, a0[j]); a1[j] = fmaf(v.y, ww, a1[j]); }
#pragma unroll
    for (int j = 0; j < 32; ++j) { float ww = wr[128 + j]; a0[j] = fmaf(u.z, ww, a0[j]); a1[j] = fmaf(v.z, ww, a1[j]); }
#pragma unroll
    for (int j = 0; j < 32; ++j) { float ww = wr[192 + j]; a0[j] = fmaf(u.w, ww, a0[j]); a1[j] = fmaf(v.w, ww, a1[j]); }
  }
}

// 1-edge, 32-out GEMM chunk
template<int K>
DEV void g1(const float* __restrict__ x, const float* __restrict__ w,
            float (&a)[32]) {
#pragma unroll 4
  for (int k = 0; k < K; k += 4) {
    const float4 u = *(const float4*)(x + k);
    const float* wr = w + (size_t)k * 64;
#pragma unroll
    for (int j = 0; j < 32; ++j) a[j] = fmaf(u.x, wr[j], a[j]);
#pragma unroll
    for (int j = 0; j < 32; ++j) a[j] = fmaf(u.y, wr[64 + j], a[j]);
#pragma unroll
    for (int j = 0; j < 32; ++j) a[j] = fmaf(u.z, wr[128 + j], a[j]);
#pragma unroll
    for (int j = 0; j < 32; ++j) a[j] = fmaf(u.w, wr[192 + j], a[j]);
  }
}

// GEMV chunk from packed-bf16 row (32 uints = 64 values)
DEV void gp32(const unsigned (&zp)[32], const float* __restrict__ w, float (&a)[32]) {
#pragma unroll 8
  for (int t = 0; t < 32; ++t) {
    const float x0 = unlo(zp[t]), x1 = unhi(zp[t]);
    const float* wr = w + (size_t)(2 * t) * 64;
#pragma unroll
    for (int j = 0; j < 32; ++j) a[j] = fmaf(x0, wr[j], a[j]);
#pragma unroll
    for (int j = 0; j < 32; ++j) a[j] = fmaf(x1, wr[64 + j], a[j]);
  }
}
// 64-out version (two 32-chunks)
DEV void gp64(const unsigned (&zp)[32], const float* __restrict__ w,
              float (&a)[32], float (&b)[32]) {
#pragma unroll 8
  for (int t = 0; t < 32; ++t) {
    const float x0 = unlo(zp[t]), x1 = unhi(zp[t]);
    const float* wr = w + (size_t)(2 * t) * 64;
#pragma unroll
    for (int j = 0; j < 32; ++j) a[j] = fmaf(x0, wr[j], a[j]);
#pragma unroll
    for (int j = 0; j < 32; ++j) b[j] = fmaf(x0, wr[32 + j], b[j]);
#pragma unroll
    for (int j = 0; j < 32; ++j) a[j] = fmaf(x1, wr[64 + j], a[j]);
#pragma unroll
    for (int j = 0; j < 32; ++j) b[j] = fmaf(x1, wr[96 + j], b[j]);
  }
}

DEV void ldrow(const unsigned* __restrict__ p, unsigned (&r)[32]) {
#pragma unroll
  for (int t = 0; t < 8; ++t) {
    uint4 u = ((const uint4*)p)[t];
    r[4*t] = u.x; r[4*t+1] = u.y; r[4*t+2] = u.z; r[4*t+3] = u.w;
  }
}
DEV void storef8(unsigned* dst, const float (&a)[32]) {   // 8 uints (fp8)
#pragma unroll
  for (int t = 0; t < 2; ++t)
    ((uint4*)dst)[t] = make_uint4(
        packf8_4(a[16*t+0],  a[16*t+1],  a[16*t+2],  a[16*t+3]),
        packf8_4(a[16*t+4],  a[16*t+5],  a[16*t+6],  a[16*t+7]),
        packf8_4(a[16*t+8],  a[16*t+9],  a[16*t+10], a[16*t+11]),
        packf8_4(a[16*t+12], a[16*t+13], a[16*t+14], a[16*t+15]));
}
DEV void storebf64(unsigned* dst, const float (&a)[64]) {  // 32 uints
#pragma unroll
  for (int t = 0; t < 8; ++t)
    ((uint4*)dst)[t] = make_uint4(pack2(a[8*t], a[8*t+1]), pack2(a[8*t+2], a[8*t+3]),
                                  pack2(a[8*t+4], a[8*t+5]), pack2(a[8*t+6], a[8*t+7]));
}
DEV void store32(float* dst, const float (&a)[32]) {
#pragma unroll
  for (int j = 0; j < 32; j += 4)
    *(float4*)(dst + j) = make_float4(a[j], a[j+1], a[j+2], a[j+3]);
}

// ---------- CSR build over edges[0] (rows) ----------
__global__ void __launch_bounds__(256)
k_count(const int* __restrict__ edges, int* __restrict__ icnt) {
  int e = blockIdx.x * 256 + threadIdx.x;
  if (e < NE) atomicAdd(&icnt[edges[e]], 1);
}

__global__ void __launch_bounds__(256)
k_scan(const int* __restrict__ icnt, int* __restrict__ ioffs) {
  __shared__ int part[256];
  const int t = threadIdx.x;
  const int base = t * 40;
  int loc[40];
  int s = 0;
#pragma unroll
  for (int i = 0; i < 40; ++i) {
    int idx = base + i;
    int v = (idx < NN) ? icnt[idx] : 0;
    loc[i] = v; s += v;
  }
  part[t] = s;
  __syncthreads();
  for (int off = 1; off < 256; off <<= 1) {
    int v = (t >= off) ? part[t - off] : 0;
    __syncthreads();
    part[t] += v;
    __syncthreads();
  }
  int run = (t == 0) ? 0 : part[t - 1];
#pragma unroll
  for (int i = 0; i < 40; ++i) {
    int idx = base + i;
    if (idx < NN) { ioffs[idx] = run; run += loc[i]; }
  }
  if (t == 255) ioffs[NN] = NE;
}

__global__ void __launch_bounds__(256)
k_fill(const int* __restrict__ edges, const int* __restrict__ ioffs,
       int* __restrict__ icur, int* __restrict__ eidx) {
  int e = blockIdx.x * 256 + threadIdx.x;
  if (e >= NE) return;
  int r = edges[e];
  int p = atomicAdd(&icur[r], 1);
  eidx[ioffs[r] + p] = e;
}

// ---------- chem layer 1: 272 -> 64 silu (2 edges/thread, y-split) ----------
__global__ void __launch_bounds__(128)
k_chem1(const float* __restrict__ h, const float* __restrict__ na,
        const float* __restrict__ ea, const int* __restrict__ edges,
        const float* __restrict__ w1, const float* __restrict__ b1,
        float* __restrict__ act1c) {
  const int tid = threadIdx.x;
  const int e0 = blockIdx.x * 256 + tid, e1 = e0 + 128;
  const int co = blockIdx.y * 32;
  const int r0 = edges[e0], c0 = edges[NE + e0];
  const int r1 = edges[e1], c1 = edges[NE + e1];
  float a0[32], a1[32];
#pragma unroll
  for (int j = 0; j < 32; ++j) { a0[j] = b1[co + j]; a1[j] = a0[j]; }
  g2<64>(h  + (size_t)r0 * 64, h  + (size_t)r1 * 64, w1 + co,            a0, a1);
  g2<64>(h  + (size_t)c0 * 64, h  + (size_t)c1 * 64, w1 +  64 * 64 + co, a0, a1);
  g2<64>(na + (size_t)r0 * 64, na + (size_t)r1 * 64, w1 + 128 * 64 + co, a0, a1);
  g2<64>(na + (size_t)c0 * 64, na + (size_t)c1 * 64, w1 + 192 * 64 + co, a0, a1);
  g2<16>(ea + (size_t)e0 * 16, ea + (size_t)e1 * 16, w1 + 256 * 64 + co, a0, a1);
#pragma unroll
  for (int j = 0; j < 32; ++j) { a0[j] = fsilu(a0[j]); a1[j] = fsilu(a1[j]); }
  store32(act1c + (size_t)e0 * 64 + co, a0);
  store32(act1c + (size_t)e1 * 64 + co, a1);
}

// ---------- pos layer 1: 36 -> 64 silu ----------
__global__ void __launch_bounds__(256)
k_pos1(const float* __restrict__ coord, const float* __restrict__ nv,
       const float* __restrict__ ea, const int* __restrict__ edges,
       const float* __restrict__ w1, const float* __restrict__ b1,
       float* __restrict__ act1p) {
  const int e = blockIdx.x * 256 + threadIdx.x;
  const int co = blockIdx.y * 32;
  const int r = edges[e], c = edges[NE + e];

  float dx = coord[r * 3 + 0] - coord[c * 3 + 0];
  float dy = coord[r * 3 + 1] - coord[c * 3 + 1];
  float dz = coord[r * 3 + 2] - coord[c * 3 + 2];
  float nrm = sqrtf(dx * dx + dy * dy + dz * dz);
  float inv = 1.0f / (nrm + 1e-8f);
  dx *= inv; dy *= inv; dz *= inv;
  float ir = dx * dx + dy * dy + dz * dz;

  float in[36];
#pragma unroll
  for (int v = 0; v < 5; ++v) {
    float s = 0.f;
#pragma unroll
    for (int d = 0; d < 3; ++d)
      s += nv[(size_t)r * 15 + v * 3 + d] * nv[(size_t)c * 15 + v * 3 + d];
    in[v] = s;
  }
  {
    float cexp = -0.5f;
#pragma unroll
    for (int k = 0; k < 15; ++k) { in[5 + k] = __expf(ir * cexp); cexp *= (1.0f / 2.25f); }
  }
#pragma unroll
  for (int k = 0; k < 16; k += 4) {
    float4 e4 = *(const float4*)(ea + (size_t)e * 16 + k);
    in[20 + k] = e4.x; in[21 + k] = e4.y; in[22 + k] = e4.z; in[23 + k] = e4.w;
  }

  float acc[32];
#pragma unroll
  for (int j = 0; j < 32; ++j) acc[j] = b1[co + j];
#pragma unroll
  for (int k = 0; k < 36; ++k) {
    const float x = in[k];
    const float* wr = w1 + (size_t)k * 64 + co;
#pragma unroll
    for (int j = 0; j < 32; ++j) acc[j] = fmaf(x, wr[j], acc[j]);
  }
#pragma unroll
  for (int j = 0; j < 32; ++j) acc[j] = fsilu(acc[j]);
  store32(act1p + (size_t)e * 64 + co, acc);
}

// ---------- layer 2 of both MLPs (2 edges/thread, y-split) ----------
__global__ void __launch_bounds__(128)
k_l2(const float* __restrict__ act1c, const float* __restrict__ act1p,
     const float* __restrict__ w2c, const float* __restrict__ b2c,
     const float* __restrict__ w2p, const float* __restrict__ b2p,
     float* __restrict__ chem, float* __restrict__ pos) {
  const int tid = threadIdx.x;
  const int e0 = blockIdx.x * 256 + tid, e1 = e0 + 128;
  const int co = blockIdx.y * 32;
  float a0[32], a1[32];
#pragma unroll
  for (int j = 0; j < 32; ++j) { a0[j] = b2c[co + j]; a1[j] = a0[j]; }
  g2<64>(act1c + (size_t)e0 * 64, act1c + (size_t)e1 * 64, w2c + co, a0, a1);
#pragma unroll
  for (int j = 0; j < 32; ++j) { a0[j] = fsilu(a0[j]); a1[j] = fsilu(a1[j]); }
  store32(chem + (size_t)e0 * 64 + co, a0);
  store32(chem + (size_t)e1 * 64 + co, a1);
#pragma unroll
  for (int j = 0; j < 32; ++j) { a0[j] = b2p[co + j]; a1[j] = a0[j]; }
  g2<64>(act1p + (size_t)e0 * 64, act1p + (size_t)e1 * 64, w2p + co, a0, a1);
#pragma unroll
  for (int j = 0; j < 32; ++j) { a0[j] = fsilu(a0[j]); a1[j] = fsilu(a1[j]); }
  store32(pos + (size_t)e0 * 64 + co, a0);
  store32(pos + (size_t)e1 * 64 + co, a1);
}

// ---------- fused: z (silu(chem@Wsh+b)*pos, gated) -> zb bf16; u/x heads; be[4] ----------
__global__ void __launch_bounds__(256)
k_scalars(const float* __restrict__ coord, const int* __restrict__ edges,
          const float* __restrict__ chem, const float* __restrict__ pos,
          const float* __restrict__ wsh, const float* __restrict__ bsh,
          const float* __restrict__ watt, const float* __restrict__ batt,
          const float* __restrict__ wu1, const float* __restrict__ bu1,
          const float* __restrict__ wu2, const float* __restrict__ bu2,
          const float* __restrict__ wx1, const float* __restrict__ bx1,
          const float* __restrict__ wx2, const float* __restrict__ bx2,
          const float* __restrict__ wb,
          unsigned* __restrict__ zb, float* __restrict__ be,
          float* __restrict__ x_sum, float* __restrict__ cntf) {
  const int e = blockIdx.x * 256 + threadIdx.x;
  const int r = edges[e], c = edges[NE + e];
  const float* crow = chem + (size_t)e * 64;
  const float* prow = pos  + (size_t)e * 64;

  // z = silu(chem @ wsh + bsh) * pos, full row in registers
  float zv[64];
#pragma unroll 1
  for (int cc = 0; cc < 64; cc += 32) {
    float acc[32];
#pragma unroll
    for (int j = 0; j < 32; ++j) acc[j] = bsh[cc + j];
    g1<64>(crow, wsh + cc, acc);
#pragma unroll
    for (int j = 0; j < 32; j += 4) {
      float4 p4 = *(const float4*)(prow + cc + j);
      zv[cc+j+0] = fsilu(acc[j+0]) * p4.x; zv[cc+j+1] = fsilu(acc[j+1]) * p4.y;
      zv[cc+j+2] = fsilu(acc[j+2]) * p4.z; zv[cc+j+3] = fsilu(acc[j+3]) * p4.w;
    }
  }
  // att gate (full-row dot, no atomic)
  float ap = batt[0];
#pragma unroll
  for (int k = 0; k < 64; ++k) ap = fmaf(zv[k], watt[k], ap);
  const float sg = fsig(ap);
#pragma unroll
  for (int j = 0; j < 64; ++j) zv[j] *= sg;

  unsigned* zrow = zb + (size_t)e * 32;
#pragma unroll
  for (int t = 0; t < 8; ++t)
    ((uint4*)zrow)[t] = make_uint4(pack2(zv[8*t], zv[8*t+1]), pack2(zv[8*t+2], zv[8*t+3]),
                                   pack2(zv[8*t+4], zv[8*t+5]), pack2(zv[8*t+6], zv[8*t+7]));
#pragma unroll
  for (int hd = 0; hd < 4; ++hd) {
    float b = 0.f;
#pragma unroll
    for (int k = 0; k < 64; ++k) b = fmaf(zv[k], wb[hd * 64 + k], b);
    be[(size_t)hd * NE + e] = b;
  }

  float u = bu2[0];
#pragma unroll 1
  for (int cc = 0; cc < 64; cc += 32) {
    float acc[32];
#pragma unroll
    for (int j = 0; j < 32; ++j) acc[j] = bu1[cc + j];
    g1<64>(crow, wu1 + cc, acc);
#pragma unroll
    for (int j = 0; j < 32; ++j) u = fmaf(fsilu(acc[j]), wu2[cc + j], u);
  }
  float xs = bx2[0];
#pragma unroll 1
  for (int cc = 0; cc < 64; cc += 32) {
    float acc[32];
#pragma unroll
    for (int j = 0; j < 32; ++j) acc[j] = bx1[cc + j];
    g1<64>(prow, wx1 + cc, acc);
#pragma unroll
    for (int j = 0; j < 32; ++j) xs = fmaf(fsilu(acc[j]), wx2[cc + j], xs);
  }

  float dx = coord[r * 3 + 0] - coord[c * 3 + 0];
  float dy = coord[r * 3 + 1] - coord[c * 3 + 1];
  float dz = coord[r * 3 + 2] - coord[c * 3 + 2];
  float nrm = sqrtf(dx * dx + dy * dy + dz * dz);
  float inv = 1.0f / (nrm + 1e-8f);
  float t = u * xs;
  atomicAdd(&x_sum[r * 3 + 0], dx * inv * t);
  atomicAdd(&x_sum[r * 3 + 1], dy * inv * t);
  atomicAdd(&x_sum[r * 3 + 2], dz * inv * t);
  atomicAdd(&cntf[r], 1.0f);
}

// ---------- all-head k/v projection -> interleaved fp8 records (128B: k||v) ----------
__global__ void __launch_bounds__(256)
k_proj(const unsigned* __restrict__ zb, const float* __restrict__ wk,
       const float* __restrict__ wv, unsigned* __restrict__ kvh) {
  const int e = blockIdx.x * 256 + threadIdx.x;
  const int hd = blockIdx.y;          // 0..3
  const float* wk_h = wk + hd * 4096;
  const float* wv_h = wv + hd * 4096;
  unsigned zp[32];
  ldrow(zb + (size_t)e * 32, zp);
  unsigned* rec = kvh + ((size_t)hd * NE + e) * 32;   // [k:16u | v:16u]
  float acc[32];
#pragma unroll
  for (int j = 0; j < 32; ++j) acc[j] = 0.f;
  gp32(zp, wk_h, acc);       storef8(rec, acc);
#pragma unroll
  for (int j = 0; j < 32; ++j) acc[j] = 0.f;
  gp32(zp, wk_h + 32, acc);  storef8(rec + 8, acc);
#pragma unroll
  for (int j = 0; j < 32; ++j) acc[j] = 0.f;
  gp32(zp, wv_h, acc);       storef8(rec + 16, acc);
#pragma unroll
  for (int j = 0; j < 32; ++j) acc[j] = 0.f;
  gp32(zp, wv_h + 32, acc);  storef8(rec + 24, acc);
}

// ---------- attention (all 4 heads), interleaved fp8 k||v records ----------
__global__ void __launch_bounds__(256)
k_attn(const unsigned* __restrict__ zb, const unsigned* __restrict__ kvh,
       const float* __restrict__ be, const int* __restrict__ klist,
       const float* __restrict__ wq, const float* __restrict__ wg,
       const float* __restrict__ bg, unsigned* __restrict__ hob) {
  const int e = blockIdx.x * 256 + threadIdx.x;
  const int hd = blockIdx.y;          // 0..3
  const float* wq_h = wq + hd * 4096;
  const float* wg_h = wg + hd * 4096;
  const uint4* kv4 = (const uint4*)(kvh + (size_t)hd * NE * 32);  // 8 uint4/record
  const float* bb_h = be + (size_t)hd * NE;

  unsigned zp[32];
  ldrow(zb + (size_t)e * 32, zp);

  float qa[32], qb[32];
#pragma unroll
  for (int j = 0; j < 32; ++j) { qa[j] = 0.f; qb[j] = 0.f; }
  gp64(zp, wq_h, qa, qb);
#pragma unroll
  for (int j = 0; j < 32; ++j) { qa[j] *= 0.125f; qb[j] *= 0.125f; }

  int i2[8], j2[8];
#pragma unroll
  for (int kn = 0; kn < 8; ++kn) {
    i2[kn] = klist[(size_t)e * 16 + kn];
    j2[kn] = klist[(size_t)e * 16 + 8 + kn];
  }
  // alpha pass: k-half of each record (first 4 uint4 of the 128B line)
  float alpha[8];
#pragma unroll 2
  for (int kn = 0; kn < 8; ++kn) {
    if (i2[kn] < 0) { alpha[kn] = -10000.0f; continue; }
    const uint4* kr = kv4 + (size_t)i2[kn] * 8;
    uint4 u0 = kr[0], u1 = kr[1], u2 = kr[2], u3 = kr[3];
    float d = 0.f;
    d = dot16(u0, qa,      d);
    d = dot16(u1, qa + 16, d);
    d = dot16(u2, qb,      d);
    d = dot16(u3, qb + 16, d);
    alpha[kn] = d + bb_h[j2[kn]];
  }
  float mx = alpha[0];
#pragma unroll
  for (int kn = 1; kn < 8; ++kn) mx = fmaxf(mx, alpha[kn]);
  float p[8], s = 0.f;
#pragma unroll
  for (int kn = 0; kn < 8; ++kn) { p[kn] = __expf(alpha[kn] - mx); s += p[kn]; }
  float is = 1.0f / s;
#pragma unroll
  for (int kn = 0; kn < 8; ++kn) p[kn] *= is;

  // ov pass: v-half (second 4 uint4 of the same line -> L2-hot)
  float ov[64];
#pragma unroll
  for (int j = 0; j < 64; ++j) ov[j] = 0.f;
#pragma unroll 2
  for (int kn = 0; kn < 8; ++kn) {
    int vi = (i2[kn] < 0) ? (NE - 1) : i2[kn];   // jax v[-1] wraps
    const uint4* vr = kv4 + (size_t)vi * 8 + 4;
    uint4 u0 = vr[0], u1 = vr[1], u2 = vr[2], u3 = vr[3];
    const float pk = p[kn];
    acc16(u0, pk, ov +  0);
    acc16(u1, pk, ov + 16);
    acc16(u2, pk, ov + 32);
    acc16(u3, pk, ov + 48);
  }
  // gate
  {
    float ga[32], gb2[32];
#pragma unroll
    for (int j = 0; j < 32; ++j) { ga[j] = bg[hd * 64 + j]; gb2[j] = bg[hd * 64 + 32 + j]; }
    gp64(zp, wg_h, ga, gb2);
#pragma unroll
    for (int j = 0; j < 32; ++j) { ov[j] *= fsig(ga[j]); ov[32 + j] *= fsig(gb2[j]); }
  }
  storebf64(hob + ((size_t)hd * NE + e) * 32, ov);
}

// ---------- output projection (all heads), per-edge m row (non-atomic) ----------
__global__ void __launch_bounds__(256)
k_mout(const unsigned* __restrict__ hob, const float* __restrict__ wout,
       float* __restrict__ medge) {
  const int e = blockIdx.x * 256 + threadIdx.x;
  float mm[64];
#pragma unroll
  for (int j = 0; j < 64; ++j) mm[j] = 0.f;
#pragma unroll 1
  for (int hd = 0; hd < 4; ++hd) {
    const unsigned* row = hob + ((size_t)hd * NE + e) * 32;
    unsigned hp[32];
    ldrow(row, hp);
    const float* wo = wout + (size_t)hd * 4096;
#pragma unroll 4
    for (int t = 0; t < 32; ++t) {
      const float x0 = unlo(hp[t]), x1 = unhi(hp[t]);
      const float* wr = wo + (size_t)(2 * t) * 64;
#pragma unroll
      for (int j = 0; j < 64; ++j) mm[j] = fmaf(x0, wr[j], mm[j]);
#pragma unroll
      for (int j = 0; j < 64; ++j) mm[j] = fmaf(x1, wr[64 + j], mm[j]);
    }
  }
  float* mr = medge + (size_t)e * 64;
#pragma unroll
  for (int j = 0; j < 64; j += 4)
    *(float4*)(mr + j) = make_float4(mm[j], mm[j+1], mm[j+2], mm[j+3]);
}

// ---------- CSR gather: per-node segment sum of medge ----------
__global__ void __launch_bounds__(256)
k_nodesum(const float* __restrict__ medge, const int* __restrict__ ioffs,
          const int* __restrict__ eidx, float* __restrict__ m_sum) {
  const int wid = threadIdx.x >> 6, lane = threadIdx.x & 63;
  const int n = blockIdx.x * 4 + wid;
  if (n >= NN) return;
  const int beg = ioffs[n], end = ioffs[n + 1];
  float acc = 0.f;
  for (int i = beg; i < end; ++i) {
    int e = eidx[i];
    acc += medge[(size_t)e * 64 + lane];
  }
  m_sum[(size_t)n * 64 + lane] = acc;
}

// ---------- final node update ----------
__global__ void __launch_bounds__(256)
k_final(const float* __restrict__ h, const float* __restrict__ na,
        const float* __restrict__ coord, const float* __restrict__ icoord,
        const float* __restrict__ m_sum, const float* __restrict__ x_sum,
        const float* __restrict__ cntf, const float* __restrict__ bout,
        const float* __restrict__ wh1, const float* __restrict__ bh1,
        const float* __restrict__ wh2, const float* __restrict__ bh2,
        float* __restrict__ scr, float* __restrict__ out) {
  int n = blockIdx.x * 256 + threadIdx.x;
  if (n >= NN) return;
  float cn = cntf[n];
  float invc = 1.0f / fmaxf(cn, 1.0f);
  float bsc = (cn > 0.f) ? 1.0f : 0.0f;   // empty segment => m_agg = 0 (no bout)

#pragma unroll
  for (int d = 0; d < 3; ++d)
    out[(size_t)NN * 64 + n * 3 + d] =
        0.2f * icoord[n * 3 + d] + 0.8f * coord[n * 3 + d] + x_sum[n * 3 + d] * invc;

  const float* hr = h  + (size_t)n * 64;
  const float* nr = na + (size_t)n * 64;
  const float* mr = m_sum + (size_t)n * 64;
  float* srow = scr + (size_t)n * 64;

#pragma unroll 1
  for (int cc = 0; cc < 64; cc += 32) {
    float acc[32];
#pragma unroll
    for (int j = 0; j < 32; ++j) acc[j] = bh1[cc + j];
    g1<64>(hr, wh1 + cc, acc);
    g1<64>(nr, wh1 + 64 * 64 + cc, acc);
#pragma unroll 4
    for (int k = 0; k < 64; k += 4) {
      float4 m4 = *(const float4*)(mr + k);
      float xv[4] = { fmaf(m4.x, invc, bout[k] * bsc), fmaf(m4.y, invc, bout[k+1] * bsc),
                      fmaf(m4.z, invc, bout[k+2] * bsc), fmaf(m4.w, invc, bout[k+3] * bsc) };
#pragma unroll
      for (int q = 0; q < 4; ++q) {
        const float* wr = wh1 + (size_t)(128 + k + q) * 64 + cc;
        const float x = xv[q];
#pragma unroll
        for (int j = 0; j < 32; ++j) acc[j] = fmaf(x, wr[j], acc[j]);
      }
    }
#pragma unroll
    for (int j = 0; j < 32; ++j) acc[j] = fsilu(acc[j]);
    store32(srow + cc, acc);
  }
#pragma unroll 1
  for (int cc = 0; cc < 64; cc += 32) {
    float acc[32];
#pragma unroll
    for (int j = 0; j < 32; ++j) acc[j] = bh2[cc + j];
    g1<64>(srow, wh2 + cc, acc);
#pragma unroll
    for (int j = 0; j < 32; j += 4) {
      float4 h4 = *(const float4*)(hr + cc + j);
      *(float4*)(out + (size_t)n * 64 + cc + j) =
          make_float4(acc[j] + h4.x, acc[j+1] + h4.y, acc[j+2] + h4.z, acc[j+3] + h4.w);
    }
  }
}

extern "C" void kernel_launch(void* const* d_in, const int* in_sizes, int n_in,
                              void* d_out, int out_size, void* d_ws, size_t ws_size,
                              hipStream_t stream) {
  (void)in_sizes; (void)n_in; (void)out_size; (void)ws_size;
  const float* h      = (const float*)d_in[0];
  const float* coord  = (const float*)d_in[1];
  const int*   edges  = (const int*)  d_in[2];
  const float* nvecs  = (const float*)d_in[3];
  const float* ea     = (const float*)d_in[4];
  const float* na     = (const float*)d_in[5];
  const float* icoord = (const float*)d_in[6];
  const int*   klist  = (const int*)  d_in[7];
  const float* w_chem1 = (const float*)d_in[8];
  const float* b_chem1 = (const float*)d_in[9];
  const float* w_chem2 = (const float*)d_in[10];
  const float* b_chem2 = (const float*)d_in[11];
  const float* w_pos1  = (const float*)d_in[12];
  const float* b_pos1  = (const float*)d_in[13];
  const float* w_pos2  = (const float*)d_in[14];
  const float* b_pos2  = (const float*)d_in[15];
  const float* w_sh    = (const float*)d_in[16];
  const float* b_sh    = (const float*)d_in[17];
  const float* w_att   = (const float*)d_in[18];
  const float* b_att   = (const float*)d_in[19];
  const float* wq      = (const float*)d_in[20];
  const float* wk      = (const float*)d_in[21];
  const float* wv      = (const float*)d_in[22];
  const float* wb      = (const float*)d_in[23];
  const float* wg      = (const float*)d_in[24];
  const float* bg      = (const float*)d_in[25];
  const float* w_out   = (const float*)d_in[26];
  const float* b_out   = (const float*)d_in[27];
  const float* wu1     = (const float*)d_in[28];
  const float* bu1     = (const float*)d_in[29];
  const float* wu2     = (const float*)d_in[30];
  const float* bu2     = (const float*)d_in[31];
  const float* wx1     = (const float*)d_in[32];
  const float* bx1     = (const float*)d_in[33];
  const float* wx2     = (const float*)d_in[34];
  const float* bx2     = (const float*)d_in[35];
  const float* wh1     = (const float*)d_in[36];
  const float* bh1     = (const float*)d_in[37];
  const float* wh2     = (const float*)d_in[38];
  const float* bh2     = (const float*)d_in[39];

  float* out = (float*)d_out;
  float* ws  = (float*)d_ws;
  // Phase-reused regions (NE*64 floats each):
  //  R1+R2: act1c/act1p -> kvh (4 heads, interleaved fp8, 82MB) -> medge in R1
  //  R3+R4: chem/pos    -> hob (4 heads, bf16)
  float* R1 = ws;
  float* R2 = R1 + (size_t)NE * 64;
  float* R3 = R2 + (size_t)NE * 64;
  float* R4 = R3 + (size_t)NE * 64;
  float* zbf   = R4 + (size_t)NE * 64;      // NE*32 floats (bf16 gated z)
  float* x_sum = zbf + (size_t)NE * 32;     // NN*3 (zeroed)
  float* cntf  = x_sum + (size_t)NN * 3;    // NN (zeroed)
  int*   icnt  = (int*)(cntf + NN);         // NN (zeroed)
  int*   icur  = icnt + NN;                 // NN (zeroed)
  float* m_sum = (float*)(icur + NN);       // NN*64
  float* be    = m_sum + (size_t)NN * 64;   // 4*NE
  float* nscr  = be + (size_t)4 * NE;       // NN*64
  int*   ioffs = (int*)(nscr + (size_t)NN * 64);  // NN+1
  int*   eidx  = ioffs + (NN + 1);          // NE

  unsigned* kvh = (unsigned*)R1;   // [4][NE][32] interleaved fp8 (spans R1+R2)
  unsigned* hob = (unsigned*)R3;   // [4][NE][32] bf16 (spans R3+R4)
  unsigned* zb  = (unsigned*)zbf;
  float* medge = R1;               // after attention (kvh dead)

  (void)hipMemsetAsync(x_sum, 0, ((size_t)NN * 3 + NN + NN + NN) * sizeof(float), stream);

  dim3 b128(128), b256(256);
  dim3 gs2(NE / 256, 2);
  dim3 gs4(NE / 256, 4);
  dim3 gflat(NE / 256);

  // CSR build (independent of the MLP pipeline)
  k_count<<<gflat, b256, 0, stream>>>(edges, icnt);
  k_scan <<<dim3(1), b256, 0, stream>>>(icnt, ioffs);
  k_fill <<<gflat, b256, 0, stream>>>(edges, ioffs, icur, eidx);

  k_chem1<<<gs2, b128, 0, stream>>>(h, na, ea, edges, w_chem1, b_chem1, R1);
  k_pos1 <<<gs2, b256, 0, stream>>>(coord, nvecs, ea, edges, w_pos1, b_pos1, R2);
  k_l2   <<<gs2, b128, 0, stream>>>(R1, R2, w_chem2, b_chem2, w_pos2, b_pos2, R3, R4);
  k_scalars<<<gflat, b256, 0, stream>>>(coord, edges, R3, R4, w_sh, b_sh, w_att, b_att,
                                        wu1, bu1, wu2, bu2, wx1, bx1, wx2, bx2, wb,
                                        zb, be, x_sum, cntf);
  // all 4 heads in one pass each
  k_proj <<<gs4, b256, 0, stream>>>(zb, wk, wv, kvh);
  k_attn <<<gs4, b256, 0, stream>>>(zb, kvh, be, klist, wq, wg, bg, hob);
  k_mout <<<gflat, b256, 0, stream>>>(hob, w_out, medge);
  k_nodesum<<<dim3((NN + 3) / 4), b256, 0, stream>>>(medge, ioffs, eidx, m_sum);
  k_final<<<dim3((NN + 255) / 256), b256, 0, stream>>>(h, na, coord, icoord, m_sum, x_sum,
                                                       cntf, b_out, wh1, bh1, wh2, bh2,
                                                       nscr, out);
}

// Round 15
// 1391.302 us; speedup vs baseline: 1.0333x; 1.0212x over previous
//
#include <hip/hip_runtime.h>
#include <math.h>

#define NE 160000
#define NN 10000

#define DEV __device__ __forceinline__

typedef float v2f __attribute__((ext_vector_type(2)));

DEV float fsilu(float x) { return x / (1.0f + __expf(-x)); }
DEV float fsig(float x)  { return 1.0f / (1.0f + __expf(-x)); }

// ---- bf16 pack/unpack helpers (RNE) ----
DEV unsigned pack2(float a, float b) {
  unsigned ua = __float_as_uint(a); ua += 0x7FFFu + ((ua >> 16) & 1u);
  unsigned ub = __float_as_uint(b); ub += 0x7FFFu + ((ub >> 16) & 1u);
  return (ua >> 16) | (ub & 0xFFFF0000u);
}
DEV float unlo(unsigned u) { return __uint_as_float(u << 16); }
DEV float unhi(unsigned u) { return __uint_as_float(u & 0xFFFF0000u); }

// ---- fp8 e4m3 (OCP, HW-converted) ----
DEV unsigned packf8_4(float a, float b, float c, float d) {
  int r = __builtin_amdgcn_cvt_pk_fp8_f32(a, b, 0, false);
  r = __builtin_amdgcn_cvt_pk_fp8_f32(c, d, r, true);
  return (unsigned)r;
}
template<bool HI>
DEV v2f up2(unsigned u) { return __builtin_amdgcn_cvt_pk_f32_fp8((int)u, HI); }

// dot of 16 fp8 values (one uint4) against q[0..16)
DEV float dot16(uint4 u, const float* q, float d) {
  v2f f;
  f = up2<false>(u.x); d = fmaf(f.x, q[0],  d); d = fmaf(f.y, q[1],  d);
  f = up2<true >(u.x); d = fmaf(f.x, q[2],  d); d = fmaf(f.y, q[3],  d);
  f = up2<false>(u.y); d = fmaf(f.x, q[4],  d); d = fmaf(f.y, q[5],  d);
  f = up2<true >(u.y); d = fmaf(f.x, q[6],  d); d = fmaf(f.y, q[7],  d);
  f = up2<false>(u.z); d = fmaf(f.x, q[8],  d); d = fmaf(f.y, q[9],  d);
  f = up2<true >(u.z); d = fmaf(f.x, q[10], d); d = fmaf(f.y, q[11], d);
  f = up2<false>(u.w); d = fmaf(f.x, q[12], d); d = fmaf(f.y, q[13], d);
  f = up2<true >(u.w); d = fmaf(f.x, q[14], d); d = fmaf(f.y, q[15], d);
  return d;
}
// o[0..16) += pk * fp8x16(u)
DEV void acc16(uint4 u, float pk, float* o) {
  v2f f;
  f = up2<false>(u.x); o[0]  = fmaf(pk, f.x, o[0]);  o[1]  = fmaf(pk, f.y, o[1]);
  f = up2<true >(u.x); o[2]  = fmaf(pk, f.x, o[2]);  o[3]  = fmaf(pk, f.y, o[3]);
  f = up2<false>(u.y); o[4]  = fmaf(pk, f.x, o[4]);  o[5]  = fmaf(pk, f.y, o[5]);
  f = up2<true >(u.y); o[6]  = fmaf(pk, f.x, o[6]);  o[7]  = fmaf(pk, f.y, o[7]);
  f = up2<false>(u.z); o[8]  = fmaf(pk, f.x, o[8]);  o[9]  = fmaf(pk, f.y, o[9]);
  f = up2<true >(u.z); o[10] = fmaf(pk, f.x, o[10]); o[11] = fmaf(pk, f.y, o[11]);
  f = up2<false>(u.w); o[12] = fmaf(pk, f.x, o[12]); o[13] = fmaf(pk, f.y, o[13]);
  f = up2<true >(u.w); o[14] = fmaf(pk, f.x, o[14]); o[15] = fmaf(pk, f.y, o[15]);
}

// 2-edge, 32-out GEMM chunk (w block-uniform -> s_load broadcast)
template<int K>
DEV void g2(const float* __restrict__ x0, const float* __restrict__ x1,
            const float* __restrict__ w, float (&a0)[32], float (&a1)[32]) {
#pragma unroll 4
  for (int k = 0; k < K; k += 4) {
    const float4 u = *(const float4*)(x0 + k);
    const float4 v = *(const float4*)(x1 + k);
    const float* wr = w + (size_t)k * 64;
#pragma unroll
    for (int j = 0; j < 32; ++j) { float ww = wr[j];       a0[j] = fmaf(u.x, ww, a0[j]); a1[j] = fmaf(v.x, ww, a1[j]); }
#pragma unroll
    for (int j = 0; j < 32; ++j) { float ww = wr[64 + j];  a0[j] = fmaf(u.y, ww, a0[j]); a1[j] = fmaf(v.y, ww, a1[j]); }
#pragma unroll
    for (int j = 0; j < 32; ++j) { float ww = wr[128 + j]; a0[j] = fmaf(u.z, ww, a0[j]); a1[j] = fmaf(v.z, ww, a1[j]); }
#pragma unroll
    for (int j = 0; j < 32; ++j) { float ww = wr[192 + j]; a0[j] = fmaf(u.w, ww, a0[j]); a1[j] = fmaf(v.w, ww, a1[j]); }
  }
}

// 1-edge, 32-out GEMM chunk
template<int K>
DEV void g1(const float* __restrict__ x, const float* __restrict__ w,
            float (&a)[32]) {
#pragma unroll 4
  for (int k = 0; k < K; k += 4) {
    const float4 u = *(const float4*)(x + k);
    const float* wr = w + (size_t)k * 64;
#pragma unroll
    for (int j = 0; j < 32; ++j) a[j] = fmaf(u.x, wr[j], a[j]);
#pragma unroll
    for (int j = 0; j < 32; ++j) a[j] = fmaf(u.y, wr[64 + j], a[j]);
#pragma unroll
    for (int j = 0; j < 32; ++j) a[j] = fmaf(u.z, wr[128 + j], a[j]);
#pragma unroll
    for (int j = 0; j < 32; ++j) a[j] = fmaf(u.w, wr[192 + j], a[j]);
  }
}

// GEMV chunk from packed-bf16 row (32 uints = 64 values)
DEV void gp32(const unsigned (&zp)[32], const float* __restrict__ w, float (&a)[32]) {
#pragma unroll 8
  for (int t = 0; t < 32; ++t) {
    const float x0 = unlo(zp[t]), x1 = unhi(zp[t]);
    const float* wr = w + (size_t)(2 * t) * 64;
#pragma unroll
    for (int j = 0; j < 32; ++j) a[j] = fmaf(x0, wr[j], a[j]);
#pragma unroll
    for (int j = 0; j < 32; ++j) a[j] = fmaf(x1, wr[64 + j], a[j]);
  }
}

DEV void ldrow(const unsigned* __restrict__ p, unsigned (&r)[32]) {
#pragma unroll
  for (int t = 0; t < 8; ++t) {
    uint4 u = ((const uint4*)p)[t];
    r[4*t] = u.x; r[4*t+1] = u.y; r[4*t+2] = u.z; r[4*t+3] = u.w;
  }
}
DEV void ldrow16(const unsigned* __restrict__ p, unsigned (&r)[16]) {
#pragma unroll
  for (int t = 0; t < 4; ++t) {
    uint4 u = ((const uint4*)p)[t];
    r[4*t] = u.x; r[4*t+1] = u.y; r[4*t+2] = u.z; r[4*t+3] = u.w;
  }
}
DEV void storef8(unsigned* dst, const float (&a)[32]) {   // 8 uints (fp8)
#pragma unroll
  for (int t = 0; t < 2; ++t)
    ((uint4*)dst)[t] = make_uint4(
        packf8_4(a[16*t+0],  a[16*t+1],  a[16*t+2],  a[16*t+3]),
        packf8_4(a[16*t+4],  a[16*t+5],  a[16*t+6],  a[16*t+7]),
        packf8_4(a[16*t+8],  a[16*t+9],  a[16*t+10], a[16*t+11]),
        packf8_4(a[16*t+12], a[16*t+13], a[16*t+14], a[16*t+15]));
}
DEV void storef8_64(unsigned* dst, const float (&a)[64]) {  // 16 uints (fp8)
#pragma unroll
  for (int t = 0; t < 4; ++t)
    ((uint4*)dst)[t] = make_uint4(
        packf8_4(a[16*t+0],  a[16*t+1],  a[16*t+2],  a[16*t+3]),
        packf8_4(a[16*t+4],  a[16*t+5],  a[16*t+6],  a[16*t+7]),
        packf8_4(a[16*t+8],  a[16*t+9],  a[16*t+10], a[16*t+11]),
        packf8_4(a[16*t+12], a[16*t+13], a[16*t+14], a[16*t+15]));
}
DEV void unpackf8(const unsigned (&p)[16], float (&o)[64]) {
#pragma unroll
  for (int t = 0; t < 16; ++t) {
    v2f f0 = up2<false>(p[t]);
    v2f f1 = up2<true >(p[t]);
    o[4*t+0] = f0.x; o[4*t+1] = f0.y; o[4*t+2] = f1.x; o[4*t+3] = f1.y;
  }
}
DEV void store32(float* dst, const float (&a)[32]) {
#pragma unroll
  for (int j = 0; j < 32; j += 4)
    *(float4*)(dst + j) = make_float4(a[j], a[j+1], a[j+2], a[j+3]);
}

// ---------- CSR build over edges[0] (rows) ----------
__global__ void __launch_bounds__(256)
k_count(const int* __restrict__ edges, int* __restrict__ icnt) {
  int e = blockIdx.x * 256 + threadIdx.x;
  if (e < NE) atomicAdd(&icnt[edges[e]], 1);
}

__global__ void __launch_bounds__(256)
k_scan(const int* __restrict__ icnt, int* __restrict__ ioffs) {
  __shared__ int part[256];
  const int t = threadIdx.x;
  const int base = t * 40;
  int loc[40];
  int s = 0;
#pragma unroll
  for (int i = 0; i < 40; ++i) {
    int idx = base + i;
    int v = (idx < NN) ? icnt[idx] : 0;
    loc[i] = v; s += v;
  }
  part[t] = s;
  __syncthreads();
  for (int off = 1; off < 256; off <<= 1) {
    int v = (t >= off) ? part[t - off] : 0;
    __syncthreads();
    part[t] += v;
    __syncthreads();
  }
  int run = (t == 0) ? 0 : part[t - 1];
#pragma unroll
  for (int i = 0; i < 40; ++i) {
    int idx = base + i;
    if (idx < NN) { ioffs[idx] = run; run += loc[i]; }
  }
  if (t == 255) ioffs[NN] = NE;
}

__global__ void __launch_bounds__(256)
k_fill(const int* __restrict__ edges, const int* __restrict__ ioffs,
       int* __restrict__ icur, int* __restrict__ eidx) {
  int e = blockIdx.x * 256 + threadIdx.x;
  if (e >= NE) return;
  int r = edges[e];
  int p = atomicAdd(&icur[r], 1);
  eidx[ioffs[r] + p] = e;
}

// ---------- chem layer 1: 272 -> 64 silu (2 edges/thread, y-split) ----------
__global__ void __launch_bounds__(128)
k_chem1(const float* __restrict__ h, const float* __restrict__ na,
        const float* __restrict__ ea, const int* __restrict__ edges,
        const float* __restrict__ w1, const float* __restrict__ b1,
        float* __restrict__ act1c) {
  const int tid = threadIdx.x;
  const int e0 = blockIdx.x * 256 + tid, e1 = e0 + 128;
  const int co = blockIdx.y * 32;
  const int r0 = edges[e0], c0 = edges[NE + e0];
  const int r1 = edges[e1], c1 = edges[NE + e1];
  float a0[32], a1[32];
#pragma unroll
  for (int j = 0; j < 32; ++j) { a0[j] = b1[co + j]; a1[j] = a0[j]; }
  g2<64>(h  + (size_t)r0 * 64, h  + (size_t)r1 * 64, w1 + co,            a0, a1);
  g2<64>(h  + (size_t)c0 * 64, h  + (size_t)c1 * 64, w1 +  64 * 64 + co, a0, a1);
  g2<64>(na + (size_t)r0 * 64, na + (size_t)r1 * 64, w1 + 128 * 64 + co, a0, a1);
  g2<64>(na + (size_t)c0 * 64, na + (size_t)c1 * 64, w1 + 192 * 64 + co, a0, a1);
  g2<16>(ea + (size_t)e0 * 16, ea + (size_t)e1 * 16, w1 + 256 * 64 + co, a0, a1);
#pragma unroll
  for (int j = 0; j < 32; ++j) { a0[j] = fsilu(a0[j]); a1[j] = fsilu(a1[j]); }
  store32(act1c + (size_t)e0 * 64 + co, a0);
  store32(act1c + (size_t)e1 * 64 + co, a1);
}

// ---------- pos layer 1: 36 -> 64 silu ----------
__global__ void __launch_bounds__(256)
k_pos1(const float* __restrict__ coord, const float* __restrict__ nv,
       const float* __restrict__ ea, const int* __restrict__ edges,
       const float* __restrict__ w1, const float* __restrict__ b1,
       float* __restrict__ act1p) {
  const int e = blockIdx.x * 256 + threadIdx.x;
  const int co = blockIdx.y * 32;
  const int r = edges[e], c = edges[NE + e];

  float dx = coord[r * 3 + 0] - coord[c * 3 + 0];
  float dy = coord[r * 3 + 1] - coord[c * 3 + 1];
  float dz = coord[r * 3 + 2] - coord[c * 3 + 2];
  float nrm = sqrtf(dx * dx + dy * dy + dz * dz);
  float inv = 1.0f / (nrm + 1e-8f);
  dx *= inv; dy *= inv; dz *= inv;
  float ir = dx * dx + dy * dy + dz * dz;

  float in[36];
#pragma unroll
  for (int v = 0; v < 5; ++v) {
    float s = 0.f;
#pragma unroll
    for (int d = 0; d < 3; ++d)
      s += nv[(size_t)r * 15 + v * 3 + d] * nv[(size_t)c * 15 + v * 3 + d];
    in[v] = s;
  }
  {
    float cexp = -0.5f;
#pragma unroll
    for (int k = 0; k < 15; ++k) { in[5 + k] = __expf(ir * cexp); cexp *= (1.0f / 2.25f); }
  }
#pragma unroll
  for (int k = 0; k < 16; k += 4) {
    float4 e4 = *(const float4*)(ea + (size_t)e * 16 + k);
    in[20 + k] = e4.x; in[21 + k] = e4.y; in[22 + k] = e4.z; in[23 + k] = e4.w;
  }

  float acc[32];
#pragma unroll
  for (int j = 0; j < 32; ++j) acc[j] = b1[co + j];
#pragma unroll
  for (int k = 0; k < 36; ++k) {
    const float x = in[k];
    const float* wr = w1 + (size_t)k * 64 + co;
#pragma unroll
    for (int j = 0; j < 32; ++j) acc[j] = fmaf(x, wr[j], acc[j]);
  }
#pragma unroll
  for (int j = 0; j < 32; ++j) acc[j] = fsilu(acc[j]);
  store32(act1p + (size_t)e * 64 + co, acc);
}

// ---------- layer 2 of both MLPs (2 edges/thread, y-split) ----------
__global__ void __launch_bounds__(128)
k_l2(const float* __restrict__ act1c, const float* __restrict__ act1p,
     const float* __restrict__ w2c, const float* __restrict__ b2c,
     const float* __restrict__ w2p, const float* __restrict__ b2p,
     float* __restrict__ chem, float* __restrict__ pos) {
  const int tid = threadIdx.x;
  const int e0 = blockIdx.x * 256 + tid, e1 = e0 + 128;
  const int co = blockIdx.y * 32;
  float a0[32], a1[32];
#pragma unroll
  for (int j = 0; j < 32; ++j) { a0[j] = b2c[co + j]; a1[j] = a0[j]; }
  g2<64>(act1c + (size_t)e0 * 64, act1c + (size_t)e1 * 64, w2c + co, a0, a1);
#pragma unroll
  for (int j = 0; j < 32; ++j) { a0[j] = fsilu(a0[j]); a1[j] = fsilu(a1[j]); }
  store32(chem + (size_t)e0 * 64 + co, a0);
  store32(chem + (size_t)e1 * 64 + co, a1);
#pragma unroll
  for (int j = 0; j < 32; ++j) { a0[j] = b2p[co + j]; a1[j] = a0[j]; }
  g2<64>(act1p + (size_t)e0 * 64, act1p + (size_t)e1 * 64, w2p + co, a0, a1);
#pragma unroll
  for (int j = 0; j < 32; ++j) { a0[j] = fsilu(a0[j]); a1[j] = fsilu(a1[j]); }
  store32(pos + (size_t)e0 * 64 + co, a0);
  store32(pos + (size_t)e1 * 64 + co, a1);
}

// ---------- fused: z (silu(chem@Wsh+b)*pos, gated) -> zb bf16; u/x heads; be[4] ----------
__global__ void __launch_bounds__(256)
k_scalars(const float* __restrict__ coord, const int* __restrict__ edges,
          const float* __restrict__ chem, const float* __restrict__ pos,
          const float* __restrict__ wsh, const float* __restrict__ bsh,
          const float* __restrict__ watt, const float* __restrict__ batt,
          const float* __restrict__ wu1, const float* __restrict__ bu1,
          const float* __restrict__ wu2, const float* __restrict__ bu2,
          const float* __restrict__ wx1, const float* __restrict__ bx1,
          const float* __restrict__ wx2, const float* __restrict__ bx2,
          const float* __restrict__ wb,
          unsigned* __restrict__ zb, float* __restrict__ be,
          float* __restrict__ x_sum, float* __restrict__ cntf) {
  const int e = blockIdx.x * 256 + threadIdx.x;
  const int r = edges[e], c = edges[NE + e];
  const float* crow = chem + (size_t)e * 64;
  const float* prow = pos  + (size_t)e * 64;

  // z = silu(chem @ wsh + bsh) * pos, full row in registers
  float zv[64];
#pragma unroll 1
  for (int cc = 0; cc < 64; cc += 32) {
    float acc[32];
#pragma unroll
    for (int j = 0; j < 32; ++j) acc[j] = bsh[cc + j];
    g1<64>(crow, wsh + cc, acc);
#pragma unroll
    for (int j = 0; j < 32; j += 4) {
      float4 p4 = *(const float4*)(prow + cc + j);
      zv[cc+j+0] = fsilu(acc[j+0]) * p4.x; zv[cc+j+1] = fsilu(acc[j+1]) * p4.y;
      zv[cc+j+2] = fsilu(acc[j+2]) * p4.z; zv[cc+j+3] = fsilu(acc[j+3]) * p4.w;
    }
  }
  // att gate (full-row dot, no atomic)
  float ap = batt[0];
#pragma unroll
  for (int k = 0; k < 64; ++k) ap = fmaf(zv[k], watt[k], ap);
  const float sg = fsig(ap);
#pragma unroll
  for (int j = 0; j < 64; ++j) zv[j] *= sg;

  unsigned* zrow = zb + (size_t)e * 32;
#pragma unroll
  for (int t = 0; t < 8; ++t)
    ((uint4*)zrow)[t] = make_uint4(pack2(zv[8*t], zv[8*t+1]), pack2(zv[8*t+2], zv[8*t+3]),
                                   pack2(zv[8*t+4], zv[8*t+5]), pack2(zv[8*t+6], zv[8*t+7]));
  // per-head b scalars, layout [e*4 + hd] (16B contiguous per edge)
  {
    float bb[4];
#pragma unroll
    for (int hd = 0; hd < 4; ++hd) {
      float b = 0.f;
#pragma unroll
      for (int k = 0; k < 64; ++k) b = fmaf(zv[k], wb[hd * 64 + k], b);
      bb[hd] = b;
    }
    *(float4*)(be + (size_t)e * 4) = make_float4(bb[0], bb[1], bb[2], bb[3]);
  }

  float u = bu2[0];
#pragma unroll 1
  for (int cc = 0; cc < 64; cc += 32) {
    float acc[32];
#pragma unroll
    for (int j = 0; j < 32; ++j) acc[j] = bu1[cc + j];
    g1<64>(crow, wu1 + cc, acc);
#pragma unroll
    for (int j = 0; j < 32; ++j) u = fmaf(fsilu(acc[j]), wu2[cc + j], u);
  }
  float xs = bx2[0];
#pragma unroll 1
  for (int cc = 0; cc < 64; cc += 32) {
    float acc[32];
#pragma unroll
    for (int j = 0; j < 32; ++j) acc[j] = bx1[cc + j];
    g1<64>(prow, wx1 + cc, acc);
#pragma unroll
    for (int j = 0; j < 32; ++j) xs = fmaf(fsilu(acc[j]), wx2[cc + j], xs);
  }

  float dx = coord[r * 3 + 0] - coord[c * 3 + 0];
  float dy = coord[r * 3 + 1] - coord[c * 3 + 1];
  float dz = coord[r * 3 + 2] - coord[c * 3 + 2];
  float nrm = sqrtf(dx * dx + dy * dy + dz * dz);
  float inv = 1.0f / (nrm + 1e-8f);
  float t = u * xs;
  atomicAdd(&x_sum[r * 3 + 0], dx * inv * t);
  atomicAdd(&x_sum[r * 3 + 1], dy * inv * t);
  atomicAdd(&x_sum[r * 3 + 2], dz * inv * t);
  atomicAdd(&cntf[r], 1.0f);
}

// ---------- per-head projections: k,v -> kvh[e*4+hd]; q -> qho; g(sigmoid) -> gf8 ----------
__global__ void __launch_bounds__(256)
k_proj(const unsigned* __restrict__ zb,
       const float* __restrict__ wk, const float* __restrict__ wv,
       const float* __restrict__ wq, const float* __restrict__ wg,
       const float* __restrict__ bg,
       unsigned* __restrict__ kvh, unsigned* __restrict__ qho,
       unsigned* __restrict__ gf8) {
  const int e = blockIdx.x * 256 + threadIdx.x;
  const int hd = blockIdx.y;          // 0..3 (block-uniform weights)
  const size_t rec = (size_t)e * 4 + hd;
  const float* wk_h = wk + hd * 4096;
  const float* wv_h = wv + hd * 4096;
  const float* wq_h = wq + hd * 4096;
  const float* wg_h = wg + hd * 4096;
  unsigned zp[32];
  ldrow(zb + (size_t)e * 32, zp);
  unsigned* kv = kvh + rec * 32;   // [k:16u | v:16u]
  float acc[32];
#pragma unroll
  for (int j = 0; j < 32; ++j) acc[j] = 0.f;
  gp32(zp, wk_h, acc);       storef8(kv, acc);
#pragma unroll
  for (int j = 0; j < 32; ++j) acc[j] = 0.f;
  gp32(zp, wk_h + 32, acc);  storef8(kv + 8, acc);
#pragma unroll
  for (int j = 0; j < 32; ++j) acc[j] = 0.f;
  gp32(zp, wv_h, acc);       storef8(kv + 16, acc);
#pragma unroll
  for (int j = 0; j < 32; ++j) acc[j] = 0.f;
  gp32(zp, wv_h + 32, acc);  storef8(kv + 24, acc);
  // q (unscaled)
  unsigned* qr = qho + rec * 16;
#pragma unroll
  for (int j = 0; j < 32; ++j) acc[j] = 0.f;
  gp32(zp, wq_h, acc);       storef8(qr, acc);
#pragma unroll
  for (int j = 0; j < 32; ++j) acc[j] = 0.f;
  gp32(zp, wq_h + 32, acc);  storef8(qr + 8, acc);
  // g = sigmoid(z@wg + bg)
  unsigned* gr = gf8 + rec * 16;
#pragma unroll
  for (int j = 0; j < 32; ++j) acc[j] = bg[hd * 64 + j];
  gp32(zp, wg_h, acc);
#pragma unroll
  for (int j = 0; j < 32; ++j) acc[j] = fsig(acc[j]);
  storef8(gr, acc);
#pragma unroll
  for (int j = 0; j < 32; ++j) acc[j] = bg[hd * 64 + 32 + j];
  gp32(zp, wg_h + 32, acc);
#pragma unroll
  for (int j = 0; j < 32; ++j) acc[j] = fsig(acc[j]);
  storef8(gr + 8, acc);
}

// ---------- attention: flat grid, lane quad = 4 heads of one edge ----------
// gathers at [i2*4+hd] -> 4 lanes read 512B contiguous; ho fp8 overwrites q slot
__global__ void __launch_bounds__(256)
k_attn(unsigned* __restrict__ qho, const unsigned* __restrict__ gf8,
       const unsigned* __restrict__ kvh, const float* __restrict__ be,
       const int* __restrict__ klist) {
  const int t = blockIdx.x * 256 + threadIdx.x;
  const int e = t >> 2, hd = t & 3;

  // q (fp8 -> fp32, unscaled)
  float q[64];
  {
    unsigned qp[16];
    ldrow16(qho + (size_t)t * 16, qp);
    unpackf8(qp, q);
  }

  int i2[8], j2[8];
#pragma unroll
  for (int kn = 0; kn < 8; ++kn) {
    i2[kn] = klist[(size_t)e * 16 + kn];
    j2[kn] = klist[(size_t)e * 16 + 8 + kn];
  }
  float bv[8];
#pragma unroll
  for (int kn = 0; kn < 8; ++kn)
    bv[kn] = be[(size_t)((i2[kn] < 0) ? 0 : j2[kn]) * 4 + hd];

  const uint4* kv4 = (const uint4*)kvh;   // 8 uint4 per record
  float alpha[8];
#pragma unroll 2
  for (int kn = 0; kn < 8; ++kn) {
    if (i2[kn] < 0) { alpha[kn] = -10000.0f; continue; }
    const uint4* kr = kv4 + ((size_t)i2[kn] * 4 + hd) * 8;
    uint4 u0 = kr[0], u1 = kr[1], u2 = kr[2], u3 = kr[3];
    float d = 0.f;
    d = dot16(u0, q,      d);
    d = dot16(u1, q + 16, d);
    d = dot16(u2, q + 32, d);
    d = dot16(u3, q + 48, d);
    alpha[kn] = d * 0.125f + bv[kn];
  }
  float mx = alpha[0];
#pragma unroll
  for (int kn = 1; kn < 8; ++kn) mx = fmaxf(mx, alpha[kn]);
  float p[8], s = 0.f;
#pragma unroll
  for (int kn = 0; kn < 8; ++kn) { p[kn] = __expf(alpha[kn] - mx); s += p[kn]; }
  float is = 1.0f / s;
#pragma unroll
  for (int kn = 0; kn < 8; ++kn) p[kn] *= is;

  float ov[64];
#pragma unroll
  for (int j = 0; j < 64; ++j) ov[j] = 0.f;
#pragma unroll 2
  for (int kn = 0; kn < 8; ++kn) {
    int vi = (i2[kn] < 0) ? (NE - 1) : i2[kn];   // jax v[-1] wraps
    const uint4* vr = kv4 + ((size_t)vi * 4 + hd) * 8 + 4;
    uint4 u0 = vr[0], u1 = vr[1], u2 = vr[2], u3 = vr[3];
    const float pk = p[kn];
    acc16(u0, pk, ov +  0);
    acc16(u1, pk, ov + 16);
    acc16(u2, pk, ov + 32);
    acc16(u3, pk, ov + 48);
  }
  // gate (precomputed sigmoid, fp8)
  {
    unsigned gp[16];
    ldrow16(gf8 + (size_t)t * 16, gp);
    float g[64];
    unpackf8(gp, g);
#pragma unroll
    for (int j = 0; j < 64; ++j) ov[j] *= g[j];
  }
  // ho fp8 -> same slot as q (thread-private)
  storef8_64(qho + (size_t)t * 16, ov);
}

// ---------- output projection (all heads), per-edge m row (non-atomic) ----------
__global__ void __launch_bounds__(256)
k_mout(const unsigned* __restrict__ qho, const float* __restrict__ wout,
       float* __restrict__ medge) {
  const int e = blockIdx.x * 256 + threadIdx.x;
  float mm[64];
#pragma unroll
  for (int j = 0; j < 64; ++j) mm[j] = 0.f;
#pragma unroll 1
  for (int hd = 0; hd < 4; ++hd) {
    unsigned hp[16];
    ldrow16(qho + ((size_t)e * 4 + hd) * 16, hp);
    const float* wo = wout + (size_t)hd * 4096;
#pragma unroll 4
    for (int t = 0; t < 16; ++t) {
      v2f f0 = up2<false>(hp[t]);
      v2f f1 = up2<true >(hp[t]);
      const float* wr = wo + (size_t)(4 * t) * 64;
#pragma unroll
      for (int j = 0; j < 64; ++j) mm[j] = fmaf(f0.x, wr[j], mm[j]);
#pragma unroll
      for (int j = 0; j < 64; ++j) mm[j] = fmaf(f0.y, wr[64 + j], mm[j]);
#pragma unroll
      for (int j = 0; j < 64; ++j) mm[j] = fmaf(f1.x, wr[128 + j], mm[j]);
#pragma unroll
      for (int j = 0; j < 64; ++j) mm[j] = fmaf(f1.y, wr[192 + j], mm[j]);
    }
  }
  float* mr = medge + (size_t)e * 64;
#pragma unroll
  for (int j = 0; j < 64; j += 4)
    *(float4*)(mr + j) = make_float4(mm[j], mm[j+1], mm[j+2], mm[j+3]);
}

// ---------- CSR gather: per-node segment sum of medge ----------
__global__ void __launch_bounds__(256)
k_nodesum(const float* __restrict__ medge, const int* __restrict__ ioffs,
          const int* __restrict__ eidx, float* __restrict__ m_sum) {
  const int wid = threadIdx.x >> 6, lane = threadIdx.x & 63;
  const int n = blockIdx.x * 4 + wid;
  if (n >= NN) return;
  const int beg = ioffs[n], end = ioffs[n + 1];
  float acc = 0.f;
  for (int i = beg; i < end; ++i) {
    int e = eidx[i];
    acc += medge[(size_t)e * 64 + lane];
  }
  m_sum[(size_t)n * 64 + lane] = acc;
}

// ---------- final node update ----------
__global__ void __launch_bounds__(256)
k_final(const float* __restrict__ h, const float* __restrict__ na,
        const float* __restrict__ coord, const float* __restrict__ icoord,
        const float* __restrict__ m_sum, const float* __restrict__ x_sum,
        const float* __restrict__ cntf, const float* __restrict__ bout,
        const float* __restrict__ wh1, const float* __restrict__ bh1,
        const float* __restrict__ wh2, const float* __restrict__ bh2,
        float* __restrict__ scr, float* __restrict__ out) {
  int n = blockIdx.x * 256 + threadIdx.x;
  if (n >= NN) return;
  float cn = cntf[n];
  float invc = 1.0f / fmaxf(cn, 1.0f);
  float bsc = (cn > 0.f) ? 1.0f : 0.0f;   // empty segment => m_agg = 0 (no bout)

#pragma unroll
  for (int d = 0; d < 3; ++d)
    out[(size_t)NN * 64 + n * 3 + d] =
        0.2f * icoord[n * 3 + d] + 0.8f * coord[n * 3 + d] + x_sum[n * 3 + d] * invc;

  const float* hr = h  + (size_t)n * 64;
  const float* nr = na + (size_t)n * 64;
  const float* mr = m_sum + (size_t)n * 64;
  float* srow = scr + (size_t)n * 64;

#pragma unroll 1
  for (int cc = 0; cc < 64; cc += 32) {
    float acc[32];
#pragma unroll
    for (int j = 0; j < 32; ++j) acc[j] = bh1[cc + j];
    g1<64>(hr, wh1 + cc, acc);
    g1<64>(nr, wh1 + 64 * 64 + cc, acc);
#pragma unroll 4
    for (int k = 0; k < 64; k += 4) {
      float4 m4 = *(const float4*)(mr + k);
      float xv[4] = { fmaf(m4.x, invc, bout[k] * bsc), fmaf(m4.y, invc, bout[k+1] * bsc),
                      fmaf(m4.z, invc, bout[k+2] * bsc), fmaf(m4.w, invc, bout[k+3] * bsc) };
#pragma unroll
      for (int q = 0; q < 4; ++q) {
        const float* wr = wh1 + (size_t)(128 + k + q) * 64 + cc;
        const float x = xv[q];
#pragma unroll
        for (int j = 0; j < 32; ++j) acc[j] = fmaf(x, wr[j], acc[j]);
      }
    }
#pragma unroll
    for (int j = 0; j < 32; ++j) acc[j] = fsilu(acc[j]);
    store32(srow + cc, acc);
  }
#pragma unroll 1
  for (int cc = 0; cc < 64; cc += 32) {
    float acc[32];
#pragma unroll
    for (int j = 0; j < 32; ++j) acc[j] = bh2[cc + j];
    g1<64>(srow, wh2 + cc, acc);
#pragma unroll
    for (int j = 0; j < 32; j += 4) {
      float4 h4 = *(const float4*)(hr + cc + j);
      *(float4*)(out + (size_t)n * 64 + cc + j) =
          make_float4(acc[j] + h4.x, acc[j+1] + h4.y, acc[j+2] + h4.z, acc[j+3] + h4.w);
    }
  }
}

extern "C" void kernel_launch(void* const* d_in, const int* in_sizes, int n_in,
                              void* d_out, int out_size, void* d_ws, size_t ws_size,
                              hipStream_t stream) {
  (void)in_sizes; (void)n_in; (void)out_size; (void)ws_size;
  const float* h      = (const float*)d_in[0];
  const float* coord  = (const float*)d_in[1];
  const int*   edges  = (const int*)  d_in[2];
  const float* nvecs  = (const float*)d_in[3];
  const float* ea     = (const float*)d_in[4];
  const float* na     = (const float*)d_in[5];
  const float* icoord = (const float*)d_in[6];
  const int*   klist  = (const int*)  d_in[7];
  const float* w_chem1 = (const float*)d_in[8];
  const float* b_chem1 = (const float*)d_in[9];
  const float* w_chem2 = (const float*)d_in[10];
  const float* b_chem2 = (const float*)d_in[11];
  const float* w_pos1  = (const float*)d_in[12];
  const float* b_pos1  = (const float*)d_in[13];
  const float* w_pos2  = (const float*)d_in[14];
  const float* b_pos2  = (const float*)d_in[15];
  const float* w_sh    = (const float*)d_in[16];
  const float* b_sh    = (const float*)d_in[17];
  const float* w_att   = (const float*)d_in[18];
  const float* b_att   = (const float*)d_in[19];
  const float* wq      = (const float*)d_in[20];
  const float* wk      = (const float*)d_in[21];
  const float* wv      = (const float*)d_in[22];
  const float* wb      = (const float*)d_in[23];
  const float* wg      = (const float*)d_in[24];
  const float* bg      = (const float*)d_in[25];
  const float* w_out   = (const float*)d_in[26];
  const float* b_out   = (const float*)d_in[27];
  const float* wu1     = (const float*)d_in[28];
  const float* bu1     = (const float*)d_in[29];
  const float* wu2     = (const float*)d_in[30];
  const float* bu2     = (const float*)d_in[31];
  const float* wx1     = (const float*)d_in[32];
  const float* bx1     = (const float*)d_in[33];
  const float* wx2     = (const float*)d_in[34];
  const float* bx2     = (const float*)d_in[35];
  const float* wh1     = (const float*)d_in[36];
  const float* bh1     = (const float*)d_in[37];
  const float* wh2     = (const float*)d_in[38];
  const float* bh2     = (const float*)d_in[39];

  float* out = (float*)d_out;
  float* ws  = (float*)d_ws;
  // Phase-reused regions (NE*64 floats each):
  //  R1+R2: act1c/act1p -> kvh [e*4+hd] fp8 (82MB) -> medge in R1 after attn
  //  R3:    chem        -> qho [e*4+hd] fp8 q, then ho in-place
  //  R4:    pos         -> gf8 [e*4+hd] fp8 sigmoid-gate
  float* R1 = ws;
  float* R2 = R1 + (size_t)NE * 64;
  float* R3 = R2 + (size_t)NE * 64;
  float* R4 = R3 + (size_t)NE * 64;
  float* zbf   = R4 + (size_t)NE * 64;      // NE*32 floats (bf16 gated z)
  float* x_sum = zbf + (size_t)NE * 32;     // NN*3 (zeroed)
  float* cntf  = x_sum + (size_t)NN * 3;    // NN (zeroed)
  int*   icnt  = (int*)(cntf + NN);         // NN (zeroed)
  int*   icur  = icnt + NN;                 // NN (zeroed)
  float* m_sum = (float*)(icur + NN);       // NN*64
  float* be    = m_sum + (size_t)NN * 64;   // 4*NE  ([e*4+hd] layout)
  float* nscr  = be + (size_t)4 * NE;       // NN*64
  int*   ioffs = (int*)(nscr + (size_t)NN * 64);  // NN+1
  int*   eidx  = ioffs + (NN + 1);          // NE

  unsigned* kvh = (unsigned*)R1;   // [NE*4][32] interleaved fp8 (spans R1+R2)
  unsigned* qho = (unsigned*)R3;   // [NE*4][16] fp8 q -> ho
  unsigned* gf8 = (unsigned*)R4;   // [NE*4][16] fp8 gate
  unsigned* zb  = (unsigned*)zbf;
  float* medge = R1;               // after attention (kvh dead)

  (void)hipMemsetAsync(x_sum, 0, ((size_t)NN * 3 + NN + NN + NN) * sizeof(float), stream);

  dim3 b128(128), b256(256);
  dim3 gs2(NE / 256, 2);
  dim3 gs4(NE / 256, 4);
  dim3 gflat(NE / 256);

  // CSR build (independent of the MLP pipeline)
  k_count<<<gflat, b256, 0, stream>>>(edges, icnt);
  k_scan <<<dim3(1), b256, 0, stream>>>(icnt, ioffs);
  k_fill <<<gflat, b256, 0, stream>>>(edges, ioffs, icur, eidx);

  k_chem1<<<gs2, b128, 0, stream>>>(h, na, ea, edges, w_chem1, b_chem1, R1);
  k_pos1 <<<gs2, b256, 0, stream>>>(coord, nvecs, ea, edges, w_pos1, b_pos1, R2);
  k_l2   <<<gs2, b128, 0, stream>>>(R1, R2, w_chem2, b_chem2, w_pos2, b_pos2, R3, R4);
  k_scalars<<<gflat, b256, 0, stream>>>(coord, edges, R3, R4, w_sh, b_sh, w_att, b_att,
                                        wu1, bu1, wu2, bu2, wx1, bx1, wx2, bx2, wb,
                                        zb, be, x_sum, cntf);
  k_proj <<<gs4, b256, 0, stream>>>(zb, wk, wv, wq, wg, bg, kvh, qho, gf8);
  k_attn <<<dim3(NE * 4 / 256), b256, 0, stream>>>(qho, gf8, kvh, be, klist);
  k_mout <<<gflat, b256, 0, stream>>>(qho, w_out, medge);
  k_nodesum<<<dim3((NN + 3) / 4), b256, 0, stream>>>(medge, ioffs, eidx, m_sum);
  k_final<<<dim3((NN + 255) / 256), b256, 0, stream>>>(h, na, coord, icoord, m_sum, x_sum,
                                                       cntf, b_out, wh1, bh1, wh2, bh2,
                                                       nscr, out);
}